// Round 2
// baseline (548.913 us; speedup 1.0000x reference)
//
#include <hip/hip_runtime.h>
#include <stdint.h>

#define LN_EPS 1e-5f

__device__ __forceinline__ float b2f(unsigned short u) {
    union { unsigned int i; float f; } v; v.i = ((unsigned int)u) << 16; return v.f;
}
__device__ __forceinline__ unsigned short f2b(float f) {
    union { float f; unsigned int i; } v; v.f = f;
    unsigned int u = v.i;
    unsigned int r = (u + 0x7fffu + ((u >> 16) & 1u)) >> 16;
    return (unsigned short)r;
}

// flags[0] = floats are f32 (else bf16); flags[1] = edge_index is int64 (else int32)
__global__ void k_detect(const unsigned short* __restrict__ xu,
                         const int* __restrict__ ei, int E, int* __restrict__ flags) {
    if (threadIdx.x == 0 && blockIdx.x == 0) {
        int cnt = 0;
        for (int i = 0; i < 2048; ++i) {
            float v = fabsf(b2f(xu[i]));
            if (v > 1e6f) ++cnt;
        }
        flags[0] = (cnt > 32) ? 1 : 0;
        int mn = (E < 1024) ? E : 1024;
        int z = 0;
        for (int i = 0; i < mn; ++i)
            if (ei[2 * i + 1] == 0) ++z;
        flags[1] = (z > (mn >> 1)) ? 1 : 0;
    }
}

// generic float convert: src (f32 or bf16 per flags[0]) -> f32
__global__ void k_cvt_f32(const void* __restrict__ src, float* __restrict__ dst, int n,
                          const int* __restrict__ flags) {
    int i = blockIdx.x * 256 + threadIdx.x;
    if (i >= n) return;
    if (flags[0]) dst[i] = ((const float*)src)[i];
    else          dst[i] = b2f(((const unsigned short*)src)[i]);
}

// edge_index (i64 or i32 per flags[1]) -> srcW/dstW int32
__global__ void k_cvt_edges(const int* __restrict__ ei, int* __restrict__ srcW,
                            int* __restrict__ dstW, int E, const int* __restrict__ flags) {
    int i = blockIdx.x * 256 + threadIdx.x;
    if (i >= E) return;
    if (flags[1]) { srcW[i] = ei[2 * i];      dstW[i] = ei[2 * E + 2 * i]; }
    else          { srcW[i] = ei[i];          dstW[i] = ei[E + i]; }
}

__global__ void k_zero_i32(int* __restrict__ p, int n) {
    int i = blockIdx.x * 256 + threadIdx.x;
    if (i < n) p[i] = 0;
}

__global__ void k_hist(const int* __restrict__ dst, int* __restrict__ deg, int E) {
    int i = blockIdx.x * 256 + threadIdx.x;
    if (i < E) atomicAdd(&deg[dst[i]], 1);
}

__global__ void k_blocksum(const int* __restrict__ deg, int* __restrict__ bsum, int n) {
    __shared__ int s[256];
    int t = threadIdx.x;
    int i = blockIdx.x * 256 + t;
    s[t] = (i < n) ? deg[i] : 0;
    __syncthreads();
    for (int d = 128; d > 0; d >>= 1) {
        if (t < d) s[t] += s[t + d];
        __syncthreads();
    }
    if (t == 0) bsum[blockIdx.x] = s[0];
}

// single-block inclusive scan of block sums -> exclusive bases; off[N] = total
__global__ void k_scan_bsum(const int* __restrict__ bsum, int* __restrict__ bbase,
                            int* __restrict__ off, int nb, int N) {
    __shared__ int s[256];
    int t = threadIdx.x;
    int v = (t < nb) ? bsum[t] : 0;
    s[t] = v;
    __syncthreads();
    for (int d = 1; d < 256; d <<= 1) {
        int x = (t >= d) ? s[t - d] : 0;
        __syncthreads();
        s[t] += x;
        __syncthreads();
    }
    if (t < nb) bbase[t] = s[t] - v;
    if (t == 255) off[N] = s[255];
}

__global__ void k_scan_tiles(int* cur, const int* __restrict__ bbase, int* __restrict__ off, int n) {
    __shared__ int s[256];
    int t = threadIdx.x;
    int i = blockIdx.x * 256 + t;
    int v = (i < n) ? cur[i] : 0;
    s[t] = v;
    __syncthreads();
    for (int d = 1; d < 256; d <<= 1) {
        int x = (t >= d) ? s[t - d] : 0;
        __syncthreads();
        s[t] += x;
        __syncthreads();
    }
    int excl = s[t] - v;
    if (i < n) {
        int val = bbase[blockIdx.x] + excl;
        off[i] = val;
        cur[i] = val;
    }
}

__global__ void k_scatter_eids(const int* __restrict__ dst, int* __restrict__ cur,
                               int* __restrict__ eids, int E) {
    int i = blockIdx.x * 256 + threadIdx.x;
    if (i < E) {
        int d = dst[i];
        int pos = atomicAdd(&cur[d], 1);
        eids[pos] = i;
    }
}

// H[n][j] = sum_k X[n][k] * Wf[k][j]; f32. 256 thr, 16 nodes/block,
// thread t -> node t>>4, cols j0=(t&15)*8 .. +7. W staged in K-chunks of 32.
__global__ __launch_bounds__(256) void k_gemm(const float* __restrict__ X,
                                              const float* __restrict__ Wf,
                                              float* __restrict__ H, int nnodes) {
    __shared__ float xs[16 * 128];   // 8 KB
    __shared__ float ws[32 * 128];   // 16 KB
    int t = threadIdx.x;
    int node0 = blockIdx.x * 16;
#pragma unroll
    for (int it = 0; it < 8; ++it) {
        int idx = t + it * 256;
        xs[idx] = X[(size_t)node0 * 128 + idx];
    }
    int node = t >> 4;
    int j0 = (t & 15) * 8;
    float acc[8];
#pragma unroll
    for (int i = 0; i < 8; ++i) acc[i] = 0.f;
    for (int c = 0; c < 4; ++c) {
        __syncthreads();
#pragma unroll
        for (int it = 0; it < 16; ++it) {
            int idx = t + it * 256;
            ws[idx] = Wf[c * 4096 + idx];
        }
        __syncthreads();
        const float* xrow = &xs[node * 128 + c * 32];
#pragma unroll 8
        for (int kk = 0; kk < 32; ++kk) {
            float xv = xrow[kk];
            float4 w0 = *(const float4*)&ws[kk * 128 + j0];
            float4 w1 = *(const float4*)&ws[kk * 128 + j0 + 4];
            acc[0] += xv * w0.x; acc[1] += xv * w0.y; acc[2] += xv * w0.z; acc[3] += xv * w0.w;
            acc[4] += xv * w1.x; acc[5] += xv * w1.y; acc[6] += xv * w1.z; acc[7] += xv * w1.w;
        }
    }
    float* out = &H[(size_t)(node0 + node) * 128 + j0];
    *(float4*)&out[0] = make_float4(acc[0], acc[1], acc[2], acc[3]);
    *(float4*)&out[4] = make_float4(acc[4], acc[5], acc[6], acc[7]);
}

// out[n][:] = bias + sum over in-edges e: ew[e] * H[src[e]][:]
// one wave per node; lane l owns features l and l+64
__global__ __launch_bounds__(256) void k_aggregate(const float* __restrict__ H,
                                                   const int* __restrict__ src,
                                                   const float* __restrict__ ew,
                                                   const int* __restrict__ off,
                                                   const int* __restrict__ eids,
                                                   const float* __restrict__ bias,
                                                   float* __restrict__ out, int nnodes) {
    int wid = threadIdx.x >> 6;
    int l = threadIdx.x & 63;
    int node = blockIdx.x * 4 + wid;
    if (node >= nnodes) return;
    float a0 = bias[l];
    float a1 = bias[64 + l];
    int beg = off[node], end = off[node + 1];
    int idx = beg;
    for (; idx + 1 < end; idx += 2) {
        int e0 = eids[idx], e1 = eids[idx + 1];
        int s0 = src[e0], s1 = src[e1];
        float w0 = ew[e0], w1 = ew[e1];
        const float* r0 = &H[(size_t)s0 * 128];
        const float* r1 = &H[(size_t)s1 * 128];
        a0 += w0 * r0[l];
        a1 += w0 * r0[l + 64];
        a0 += w1 * r1[l];
        a1 += w1 * r1[l + 64];
    }
    if (idx < end) {
        int e = eids[idx];
        int s0 = src[e];
        float w = ew[e];
        const float* r = &H[(size_t)s0 * 128];
        a0 += w * r[l];
        a1 += w * r[l + 64];
    }
    out[(size_t)node * 128 + l] = a0;
    out[(size_t)node * 128 + 64 + l] = a1;
}

// mid-layer LN+ReLU (f32 out)
__global__ __launch_bounds__(256) void k_ln_relu_mid(const float* __restrict__ in,
                                                     const float* __restrict__ g,
                                                     const float* __restrict__ be,
                                                     float* __restrict__ out, int nnodes) {
    int wid = threadIdx.x >> 6;
    int l = threadIdx.x & 63;
    int node = blockIdx.x * 4 + wid;
    if (node >= nnodes) return;
    const float* row = &in[(size_t)node * 128];
    float v0 = row[l], v1 = row[l + 64];
    float s = v0 + v1;
#pragma unroll
    for (int m = 32; m >= 1; m >>= 1) s += __shfl_xor(s, m, 64);
    float mu = s * (1.f / 128.f);
    float d0 = v0 - mu, d1 = v1 - mu;
    float q = d0 * d0 + d1 * d1;
#pragma unroll
    for (int m = 32; m >= 1; m >>= 1) q += __shfl_xor(q, m, 64);
    float rs = rsqrtf(q * (1.f / 128.f) + LN_EPS);
    out[(size_t)node * 128 + l]      = fmaxf(d0 * rs * g[l] + be[l], 0.f);
    out[(size_t)node * 128 + 64 + l] = fmaxf(d1 * rs * g[64 + l] + be[64 + l], 0.f);
}

// final LN+ReLU: writes d_out as f32 or bf16 per flags[0]
__global__ __launch_bounds__(256) void k_ln_relu_out(const float* __restrict__ in,
                                                     const float* __restrict__ g,
                                                     const float* __restrict__ be,
                                                     void* __restrict__ outAny,
                                                     const int* __restrict__ flags, int nnodes) {
    int wid = threadIdx.x >> 6;
    int l = threadIdx.x & 63;
    int node = blockIdx.x * 4 + wid;
    if (node >= nnodes) return;
    const float* row = &in[(size_t)node * 128];
    float v0 = row[l], v1 = row[l + 64];
    float s = v0 + v1;
#pragma unroll
    for (int m = 32; m >= 1; m >>= 1) s += __shfl_xor(s, m, 64);
    float mu = s * (1.f / 128.f);
    float d0 = v0 - mu, d1 = v1 - mu;
    float q = d0 * d0 + d1 * d1;
#pragma unroll
    for (int m = 32; m >= 1; m >>= 1) q += __shfl_xor(q, m, 64);
    float rs = rsqrtf(q * (1.f / 128.f) + LN_EPS);
    float r0 = fmaxf(d0 * rs * g[l] + be[l], 0.f);
    float r1 = fmaxf(d1 * rs * g[64 + l] + be[64 + l], 0.f);
    size_t i0 = (size_t)node * 128 + l;
    size_t i1 = i0 + 64;
    if (flags[0]) {
        ((float*)outAny)[i0] = r0;
        ((float*)outAny)[i1] = r1;
    } else {
        ((unsigned short*)outAny)[i0] = f2b(r0);
        ((unsigned short*)outAny)[i1] = f2b(r1);
    }
}

extern "C" void kernel_launch(void* const* d_in, const int* in_sizes, int n_in,
                              void* d_out, int out_size, void* d_ws, size_t ws_size,
                              hipStream_t stream) {
    const unsigned short* x_u16 = (const unsigned short*)d_in[0];
    const int*            ei    = (const int*)d_in[1];

    const int N = in_sizes[0] / 128;
    const int E = in_sizes[2];

    // ---- workspace layout (all f32 unless noted) ----
    float* A    = (float*)d_ws;                  // N*128
    float* B    = A + (size_t)N * 128;           // N*128
    float* ewF  = B + (size_t)N * 128;           // E
    float* W1f  = ewF + E;                       // 16384
    float* W2f  = W1f + 16384;                   // 16384
    float* b1f  = W2f + 16384;                   // 128
    float* b2f_ = b1f + 128;
    float* g1f  = b2f_ + 128;
    float* g2f  = g1f + 128;
    float* be1f = g2f + 128;
    float* be2f = be1f + 128;
    int* srcW   = (int*)(be2f + 128);            // E
    int* dstW   = srcW + E;                      // E
    int* off    = dstW + E;                      // N+1 (+pad)
    int* cur    = off + (N + 4);                 // N
    int* eids   = cur + N;                       // E
    int* bsum   = eids + E;                      // 256
    int* bbase  = bsum + 256;                    // 256
    int* flags  = bbase + 256;                   // 8

    const int nb = (N + 255) / 256;
    const int eb = (E + 255) / 256;
    const int nodeBlocks = (N + 3) / 4;
    const int gemmBlocks = (N + 15) / 16;

    // ---- dtype detection ----
    k_detect<<<1, 64, 0, stream>>>(x_u16, ei, E, flags);

    // ---- convert everything to the uniform f32 pipeline ----
    k_cvt_f32<<<(N * 128 + 255) / 256, 256, 0, stream>>>(d_in[0], A, N * 128, flags);
    k_cvt_f32<<<eb, 256, 0, stream>>>(d_in[2], ewF, E, flags);
    k_cvt_f32<<<64, 256, 0, stream>>>(d_in[3], W1f, 16384, flags);
    k_cvt_f32<<<1, 128, 0, stream>>>(d_in[4], b1f, 128, flags);
    k_cvt_f32<<<64, 256, 0, stream>>>(d_in[5], W2f, 16384, flags);
    k_cvt_f32<<<1, 128, 0, stream>>>(d_in[6], b2f_, 128, flags);
    k_cvt_f32<<<1, 128, 0, stream>>>(d_in[7], g1f, 128, flags);
    k_cvt_f32<<<1, 128, 0, stream>>>(d_in[8], be1f, 128, flags);
    k_cvt_f32<<<1, 128, 0, stream>>>(d_in[9], g2f, 128, flags);
    k_cvt_f32<<<1, 128, 0, stream>>>(d_in[10], be2f, 128, flags);
    k_cvt_edges<<<eb, 256, 0, stream>>>(ei, srcW, dstW, E, flags);

    // ---- build CSR by destination (reused by both layers) ----
    k_zero_i32<<<nb, 256, 0, stream>>>(cur, N);
    k_hist<<<eb, 256, 0, stream>>>(dstW, cur, E);
    k_blocksum<<<nb, 256, 0, stream>>>(cur, bsum, N);
    k_scan_bsum<<<1, 256, 0, stream>>>(bsum, bbase, off, nb, N);
    k_scan_tiles<<<nb, 256, 0, stream>>>(cur, bbase, off, N);
    k_scatter_eids<<<eb, 256, 0, stream>>>(dstW, cur, eids, E);

    // ---- layer 1 ----
    k_gemm<<<gemmBlocks, 256, 0, stream>>>(A, W1f, B, N);
    k_aggregate<<<nodeBlocks, 256, 0, stream>>>(B, srcW, ewF, off, eids, b1f, A, N);
    k_ln_relu_mid<<<nodeBlocks, 256, 0, stream>>>(A, g1f, be1f, A, N);

    // ---- layer 2 ----
    k_gemm<<<gemmBlocks, 256, 0, stream>>>(A, W2f, B, N);
    k_aggregate<<<nodeBlocks, 256, 0, stream>>>(B, srcW, ewF, off, eids, b2f_, A, N);
    k_ln_relu_out<<<nodeBlocks, 256, 0, stream>>>(A, g2f, be2f, d_out, flags, N);
}

// Round 3
// 303.481 us; speedup vs baseline: 1.8087x; 1.8087x over previous
//
#include <hip/hip_runtime.h>
#include <stdint.h>

#define LN_EPS 1e-5f

typedef __attribute__((ext_vector_type(8))) short s16x8;
typedef __attribute__((ext_vector_type(4))) float f32x4;

__device__ __forceinline__ float b2f(unsigned short u) {
    union { unsigned int i; float f; } v; v.i = ((unsigned int)u) << 16; return v.f;
}
__device__ __forceinline__ unsigned short f2b(float f) {
    union { float f; unsigned int i; } v; v.f = f;
    unsigned int u = v.i;
    return (unsigned short)((u + 0x7fffu + ((u >> 16) & 1u)) >> 16);
}
__device__ __forceinline__ unsigned int pk2(float a, float b) {
    return (unsigned int)f2b(a) | ((unsigned int)f2b(b) << 16);
}

// flags[0] = floats are f32 (else bf16); flags[1] = edge_index is int64 (else int32)
__global__ void k_detect(const unsigned short* __restrict__ xu,
                         const int* __restrict__ ei, int E, int* __restrict__ flags) {
    __shared__ int s[2];
    int t = threadIdx.x;
    if (t < 2) s[t] = 0;
    __syncthreads();
    int c1 = 0;
    for (int i = t; i < 2048; i += 256)
        if (fabsf(b2f(xu[i])) > 1e6f) ++c1;
    if (c1) atomicAdd(&s[0], c1);
    int mn = (E < 1024) ? E : 1024;
    int z = 0;
    for (int i = t; i < mn; i += 256)
        if (ei[2 * i + 1] == 0) ++z;
    if (z) atomicAdd(&s[1], z);
    __syncthreads();
    if (t == 0) {
        flags[0] = (s[0] > 32) ? 1 : 0;
        flags[1] = (s[1] > (mn >> 1)) ? 1 : 0;
    }
}

__device__ __forceinline__ float rdf(const void* p, int i, int f32flag) {
    return f32flag ? ((const float*)p)[i] : b2f(((const unsigned short*)p)[i]);
}

// one block: W1,W2 -> transposed bf16 (Wt[j][k]); bias/gamma/beta -> f32
__global__ void k_prep(const void* W1, const void* W2,
                       const void* b1, const void* b2,
                       const void* g1, const void* g2,
                       const void* be1, const void* be2,
                       unsigned short* __restrict__ Wt1, unsigned short* __restrict__ Wt2,
                       float* __restrict__ sm, // b1f,b2f,g1f,g2f,be1f,be2f each 128
                       const int* __restrict__ flags) {
    int t = threadIdx.x;
    int f = flags[0];
    for (int i = t; i < 16384; i += 256) {
        int k = i >> 7, j = i & 127;
        Wt1[j * 128 + k] = f2b(rdf(W1, i, f));
        Wt2[j * 128 + k] = f2b(rdf(W2, i, f));
    }
    if (t < 128) {
        sm[t]       = rdf(b1, t, f);
        sm[128 + t] = rdf(b2, t, f);
        sm[256 + t] = rdf(g1, t, f);
        sm[384 + t] = rdf(g2, t, f);
        sm[512 + t] = rdf(be1, t, f);
        sm[640 + t] = rdf(be2, t, f);
    }
}

__global__ void k_cvt_f32(const void* __restrict__ src, float* __restrict__ dst, int n,
                          const int* __restrict__ flags) {
    int i = blockIdx.x * 256 + threadIdx.x;
    if (i >= n) return;
    dst[i] = rdf(src, i, flags[0]);
}

__global__ void k_zero_i32(int* __restrict__ p, int n) {
    int i = blockIdx.x * 256 + threadIdx.x;
    if (i < n) p[i] = 0;
}

__device__ __forceinline__ int ld_dst(const int* ei, int i, int E, int f64) {
    return f64 ? ei[2 * E + 2 * i] : ei[E + i];
}

__global__ void k_hist(const int* __restrict__ ei, int* __restrict__ deg, int E,
                       const int* __restrict__ flags) {
    int i = blockIdx.x * 256 + threadIdx.x;
    if (i < E) atomicAdd(&deg[ld_dst(ei, i, E, flags[1])], 1);
}

__global__ void k_blocksum(const int* __restrict__ deg, int* __restrict__ bsum, int n) {
    __shared__ int s[256];
    int t = threadIdx.x;
    int i = blockIdx.x * 256 + t;
    s[t] = (i < n) ? deg[i] : 0;
    __syncthreads();
    for (int d = 128; d > 0; d >>= 1) {
        if (t < d) s[t] += s[t + d];
        __syncthreads();
    }
    if (t == 0) bsum[blockIdx.x] = s[0];
}

__global__ void k_scan_bsum(const int* __restrict__ bsum, int* __restrict__ bbase,
                            int* __restrict__ off, int nb, int N) {
    __shared__ int s[256];
    int t = threadIdx.x;
    int v = (t < nb) ? bsum[t] : 0;
    s[t] = v;
    __syncthreads();
    for (int d = 1; d < 256; d <<= 1) {
        int x = (t >= d) ? s[t - d] : 0;
        __syncthreads();
        s[t] += x;
        __syncthreads();
    }
    if (t < nb) bbase[t] = s[t] - v;
    if (t == 255) off[N] = s[255];
}

__global__ void k_scan_tiles(int* cur, const int* __restrict__ bbase, int* __restrict__ off, int n) {
    __shared__ int s[256];
    int t = threadIdx.x;
    int i = blockIdx.x * 256 + t;
    int v = (i < n) ? cur[i] : 0;
    s[t] = v;
    __syncthreads();
    for (int d = 1; d < 256; d <<= 1) {
        int x = (t >= d) ? s[t - d] : 0;
        __syncthreads();
        s[t] += x;
        __syncthreads();
    }
    int excl = s[t] - v;
    if (i < n) {
        int val = bbase[blockIdx.x] + excl;
        off[i] = val;
        cur[i] = val;
    }
}

// scatter packed (src, ew_bits) into CSR slots
__global__ void k_scatter(const int* __restrict__ ei, const void* __restrict__ ew,
                          int* __restrict__ cur, int2* __restrict__ edata, int E,
                          const int* __restrict__ flags) {
    int i = blockIdx.x * 256 + threadIdx.x;
    if (i >= E) return;
    int f64 = flags[1];
    int d = ld_dst(ei, i, E, f64);
    int s = f64 ? ei[2 * i] : ei[i];
    float w = rdf(ew, i, flags[0]);
    int pos = atomicAdd(&cur[d], 1);
    edata[pos] = make_int2(s, __float_as_int(w));
}

// MFMA bf16 GEMM: H[n][j] = sum_k X[n][k]*W[k][j]; Wt is bf16 [j][k] (transposed).
// 64 nodes/block, 256 thr = 4 waves; wave w: rows w*16..+15 x all 128 cols.
__global__ __launch_bounds__(256) void k_gemm(const float* __restrict__ X,
                                              const unsigned short* __restrict__ Wt,
                                              float* __restrict__ H, int N) {
    __shared__ unsigned char lds[49152];   // xs 16KB (64x128 bf16) + wt 32KB (128x128 bf16)
    unsigned char* xs = lds;
    unsigned char* wt = lds + 16384;
    int t = threadIdx.x;
    int node0 = blockIdx.x * 64;

    // stage Wt (bf16, row-major [col][k]) -> LDS, XOR-swizzled (T2)
#pragma unroll
    for (int it = 0; it < 8; ++it) {
        int c = t + it * 256;
        int row = c >> 4, cc = c & 15;
        uint4 v = *(const uint4*)(Wt + row * 128 + cc * 8);
        int off = (row * 256 + cc * 16) ^ ((row & 7) << 4);
        *(uint4*)(wt + off) = v;
    }
    // stage X rows (f32 -> bf16) -> LDS, same swizzle
#pragma unroll
    for (int it = 0; it < 4; ++it) {
        int c = t + it * 256;
        int row = c >> 4, cc = c & 15;
        int g = node0 + row;
        float4 f0 = make_float4(0.f, 0.f, 0.f, 0.f), f1 = f0;
        if (g < N) {
            f0 = *(const float4*)(X + (size_t)g * 128 + cc * 8);
            f1 = *(const float4*)(X + (size_t)g * 128 + cc * 8 + 4);
        }
        uint4 v;
        v.x = pk2(f0.x, f0.y); v.y = pk2(f0.z, f0.w);
        v.z = pk2(f1.x, f1.y); v.w = pk2(f1.z, f1.w);
        int off = (row * 256 + cc * 16) ^ ((row & 7) << 4);
        *(uint4*)(xs + off) = v;
    }
    __syncthreads();

    int w = t >> 6, l = t & 63;
    int arow = l & 15;          // A row / B col / D col
    int apart = l >> 4;         // k sub-block 0..3
    f32x4 acc[8];
#pragma unroll
    for (int ct = 0; ct < 8; ++ct) acc[ct] = (f32x4){0.f, 0.f, 0.f, 0.f};

#pragma unroll
    for (int ks = 0; ks < 4; ++ks) {
        int grow = w * 16 + arow;
        int aoff = (grow * 256 + ks * 64 + apart * 16) ^ ((grow & 7) << 4);
        s16x8 afrag = *(const s16x8*)(xs + aoff);
#pragma unroll
        for (int ct = 0; ct < 8; ++ct) {
            int brow = ct * 16 + arow;
            int boff = (brow * 256 + ks * 64 + apart * 16) ^ ((brow & 7) << 4);
            s16x8 bfrag = *(const s16x8*)(wt + boff);
            acc[ct] = __builtin_amdgcn_mfma_f32_16x16x32_bf16(afrag, bfrag, acc[ct], 0, 0, 0);
        }
    }
    // D: lane holds D[(l>>4)*4 + r][l&15] of each 16x16 tile
    int orow0 = node0 + w * 16 + apart * 4;
    int ocol = arow;
#pragma unroll
    for (int ct = 0; ct < 8; ++ct) {
#pragma unroll
        for (int r = 0; r < 4; ++r) {
            int g = orow0 + r;
            if (g < N) H[(size_t)g * 128 + ct * 16 + ocol] = acc[ct][r];
        }
    }
}

// fused: out = relu(LN(bias + sum_e ew*H[src])) ; one wave per node
template <bool FINAL>
__global__ __launch_bounds__(256) void k_agg_ln(const float* __restrict__ H,
                                                const int2* __restrict__ edata,
                                                const int* __restrict__ off,
                                                const float* __restrict__ bias,
                                                const float* __restrict__ g,
                                                const float* __restrict__ be,
                                                float* __restrict__ outf,
                                                void* __restrict__ outAny,
                                                const int* __restrict__ flags, int N) {
    int wid = threadIdx.x >> 6;
    int l = threadIdx.x & 63;
    int node = blockIdx.x * 4 + wid;
    if (node >= N) return;
    float a0 = bias[l];
    float a1 = bias[64 + l];
    int idx = off[node], end = off[node + 1];
    for (; idx + 3 < end; idx += 4) {
        int2 e0 = edata[idx], e1 = edata[idx + 1], e2 = edata[idx + 2], e3 = edata[idx + 3];
        const float* r0 = H + (size_t)e0.x * 128;
        const float* r1 = H + (size_t)e1.x * 128;
        const float* r2 = H + (size_t)e2.x * 128;
        const float* r3 = H + (size_t)e3.x * 128;
        float w0 = __int_as_float(e0.y), w1 = __int_as_float(e1.y);
        float w2 = __int_as_float(e2.y), w3 = __int_as_float(e3.y);
        a0 += w0 * r0[l];      a1 += w0 * r0[l + 64];
        a0 += w1 * r1[l];      a1 += w1 * r1[l + 64];
        a0 += w2 * r2[l];      a1 += w2 * r2[l + 64];
        a0 += w3 * r3[l];      a1 += w3 * r3[l + 64];
    }
    for (; idx < end; ++idx) {
        int2 e = edata[idx];
        const float* r = H + (size_t)e.x * 128;
        float w = __int_as_float(e.y);
        a0 += w * r[l];
        a1 += w * r[l + 64];
    }
    // LayerNorm over the 128-row held as (a0,a1) across 64 lanes
    float s = a0 + a1;
#pragma unroll
    for (int m = 32; m >= 1; m >>= 1) s += __shfl_xor(s, m, 64);
    float mu = s * (1.f / 128.f);
    float d0 = a0 - mu, d1 = a1 - mu;
    float q = d0 * d0 + d1 * d1;
#pragma unroll
    for (int m = 32; m >= 1; m >>= 1) q += __shfl_xor(q, m, 64);
    float rs = rsqrtf(q * (1.f / 128.f) + LN_EPS);
    float r0 = fmaxf(d0 * rs * g[l] + be[l], 0.f);
    float r1 = fmaxf(d1 * rs * g[64 + l] + be[64 + l], 0.f);
    size_t i0 = (size_t)node * 128 + l;
    size_t i1 = i0 + 64;
    if (FINAL) {
        if (flags[0]) {
            ((float*)outAny)[i0] = r0;
            ((float*)outAny)[i1] = r1;
        } else {
            ((unsigned short*)outAny)[i0] = f2b(r0);
            ((unsigned short*)outAny)[i1] = f2b(r1);
        }
    } else {
        outf[i0] = r0;
        outf[i1] = r1;
    }
}

extern "C" void kernel_launch(void* const* d_in, const int* in_sizes, int n_in,
                              void* d_out, int out_size, void* d_ws, size_t ws_size,
                              hipStream_t stream) {
    const unsigned short* x_u16 = (const unsigned short*)d_in[0];
    const int*            ei    = (const int*)d_in[1];

    const int N = in_sizes[0] / 128;
    const int E = in_sizes[2];

    // ---- workspace layout ----
    float* A    = (float*)d_ws;                    // N*128 f32
    float* B    = A + (size_t)N * 128;             // N*128 f32
    int2* edata = (int2*)(B + (size_t)N * 128);    // E (8B each)
    int* off    = (int*)(edata + E);               // N+1 (+pad)
    int* cur    = off + (N + 4);                   // N
    int* bsum   = cur + N;                         // 256
    int* bbase  = bsum + 256;                      // 256
    int* flags  = bbase + 256;                     // 8
    unsigned short* Wt1 = (unsigned short*)(flags + 8);  // 16384 bf16
    unsigned short* Wt2 = Wt1 + 16384;                    // 16384 bf16
    float* sm   = (float*)(Wt2 + 16384);           // 6*128 f32 params
    float* b1f  = sm;
    float* b2f_ = sm + 128;
    float* g1f  = sm + 256;
    float* g2f  = sm + 384;
    float* be1f = sm + 512;
    float* be2f = sm + 640;

    const int nb = (N + 255) / 256;
    const int eb = (E + 255) / 256;
    const int nodeBlocks = (N + 3) / 4;
    const int gemmBlocks = (N + 63) / 64;

    // dtype detection (parallel)
    k_detect<<<1, 256, 0, stream>>>(x_u16, ei, E, flags);

    // param prep (W transpose->bf16, small vecs->f32)
    k_prep<<<1, 256, 0, stream>>>(d_in[3], d_in[5], d_in[4], d_in[6],
                                  d_in[7], d_in[9], d_in[8], d_in[10],
                                  Wt1, Wt2, sm, flags);

    // x -> f32 A
    k_cvt_f32<<<(N * 128 + 255) / 256, 256, 0, stream>>>(d_in[0], A, N * 128, flags);

    // CSR by destination, packed (src, ew)
    k_zero_i32<<<nb, 256, 0, stream>>>(cur, N);
    k_hist<<<eb, 256, 0, stream>>>(ei, cur, E, flags);
    k_blocksum<<<nb, 256, 0, stream>>>(cur, bsum, N);
    k_scan_bsum<<<1, 256, 0, stream>>>(bsum, bbase, off, nb, N);
    k_scan_tiles<<<nb, 256, 0, stream>>>(cur, bbase, off, N);
    k_scatter<<<eb, 256, 0, stream>>>(ei, d_in[2], cur, edata, E, flags);

    // layer 1
    k_gemm<<<gemmBlocks, 256, 0, stream>>>(A, Wt1, B, N);
    k_agg_ln<false><<<nodeBlocks, 256, 0, stream>>>(B, edata, off, b1f, g1f, be1f, A, nullptr, flags, N);

    // layer 2
    k_gemm<<<gemmBlocks, 256, 0, stream>>>(A, Wt2, B, N);
    k_agg_ln<true><<<nodeBlocks, 256, 0, stream>>>(B, edata, off, b2f_, g2f, be2f, nullptr, d_out, flags, N);
}

// Round 4
// 218.275 us; speedup vs baseline: 2.5148x; 1.3904x over previous
//
#include <hip/hip_runtime.h>
#include <stdint.h>

#define LN_EPS 1e-5f

typedef __attribute__((ext_vector_type(8))) short s16x8;
typedef __attribute__((ext_vector_type(4))) float f32x4;

__device__ __forceinline__ float b2f(unsigned short u) {
    union { unsigned int i; float f; } v; v.i = ((unsigned int)u) << 16; return v.f;
}
__device__ __forceinline__ unsigned short f2b(float f) {
    union { float f; unsigned int i; } v; v.f = f;
    unsigned int u = v.i;
    return (unsigned short)((u + 0x7fffu + ((u >> 16) & 1u)) >> 16);
}
__device__ __forceinline__ unsigned int pk2(float a, float b) {
    return (unsigned int)f2b(a) | ((unsigned int)f2b(b) << 16);
}

// flags[0] = floats are f32 (else bf16); flags[1] = edge_index is int64 (else int32)
__global__ void k_detect(const unsigned short* __restrict__ xu,
                         const int* __restrict__ ei, int E, int* __restrict__ flags) {
    __shared__ int s[2];
    int t = threadIdx.x;
    if (t < 2) s[t] = 0;
    __syncthreads();
    int c1 = 0;
    for (int i = t; i < 2048; i += 256)
        if (fabsf(b2f(xu[i])) > 1e6f) ++c1;
    if (c1) atomicAdd(&s[0], c1);
    int mn = (E < 1024) ? E : 1024;
    int z = 0;
    for (int i = t; i < mn; i += 256)
        if (ei[2 * i + 1] == 0) ++z;
    if (z) atomicAdd(&s[1], z);
    __syncthreads();
    if (t == 0) {
        flags[0] = (s[0] > 32) ? 1 : 0;
        flags[1] = (s[1] > (mn >> 1)) ? 1 : 0;
    }
}

__device__ __forceinline__ float rdf(const void* p, int i, int f32flag) {
    return f32flag ? ((const float*)p)[i] : b2f(((const unsigned short*)p)[i]);
}

// 64 blocks: W1,W2 -> transposed bf16 Wt[j][k]; block 0 also converts small params
__global__ void k_prep(const void* W1, const void* W2,
                       const void* b1, const void* b2,
                       const void* g1, const void* g2,
                       const void* be1, const void* be2,
                       unsigned short* __restrict__ Wt1, unsigned short* __restrict__ Wt2,
                       float* __restrict__ sm, const int* __restrict__ flags) {
    int t = threadIdx.x;
    int f = flags[0];
    int i = blockIdx.x * 256 + t;  // 64*256 = 16384
    int k = i >> 7, j = i & 127;
    Wt1[j * 128 + k] = f2b(rdf(W1, i, f));
    Wt2[j * 128 + k] = f2b(rdf(W2, i, f));
    if (blockIdx.x == 0 && t < 128) {
        sm[t]       = rdf(b1, t, f);
        sm[128 + t] = rdf(b2, t, f);
        sm[256 + t] = rdf(g1, t, f);
        sm[384 + t] = rdf(g2, t, f);
        sm[512 + t] = rdf(be1, t, f);
        sm[640 + t] = rdf(be2, t, f);
    }
}

// x -> bf16, 4 elems/thread
__global__ void k_cvt_x(const void* __restrict__ src, unsigned short* __restrict__ dst,
                        int n4, const int* __restrict__ flags) {
    int i = blockIdx.x * 256 + threadIdx.x;
    if (i >= n4) return;
    if (flags[0]) {
        float4 v = ((const float4*)src)[i];
        uint2 o;
        o.x = pk2(v.x, v.y);
        o.y = pk2(v.z, v.w);
        ((uint2*)dst)[i] = o;
    } else {
        ((uint2*)dst)[i] = ((const uint2*)src)[i];
    }
}

__global__ void k_zero_i32(int* __restrict__ p, int n) {
    int i = blockIdx.x * 256 + threadIdx.x;
    if (i < n) p[i] = 0;
}

__device__ __forceinline__ int ld_dst(const int* ei, int i, int E, int f64) {
    return f64 ? ei[2 * E + 2 * i] : ei[E + i];
}

__global__ void k_hist(const int* __restrict__ ei, int* __restrict__ deg, int E,
                       const int* __restrict__ flags) {
    int i = blockIdx.x * 256 + threadIdx.x;
    if (i < E) atomicAdd(&deg[ld_dst(ei, i, E, flags[1])], 1);
}

__global__ void k_blocksum(const int* __restrict__ deg, int* __restrict__ bsum, int n) {
    __shared__ int s[256];
    int t = threadIdx.x;
    int i = blockIdx.x * 256 + t;
    s[t] = (i < n) ? deg[i] : 0;
    __syncthreads();
    for (int d = 128; d > 0; d >>= 1) {
        if (t < d) s[t] += s[t + d];
        __syncthreads();
    }
    if (t == 0) bsum[blockIdx.x] = s[0];
}

__global__ void k_scan_bsum(const int* __restrict__ bsum, int* __restrict__ bbase,
                            int* __restrict__ off, int nb, int N) {
    __shared__ int s[256];
    int t = threadIdx.x;
    int v = (t < nb) ? bsum[t] : 0;
    s[t] = v;
    __syncthreads();
    for (int d = 1; d < 256; d <<= 1) {
        int x = (t >= d) ? s[t - d] : 0;
        __syncthreads();
        s[t] += x;
        __syncthreads();
    }
    if (t < nb) bbase[t] = s[t] - v;
    if (t == 255) off[N] = s[255];
}

__global__ void k_scan_tiles(int* cur, const int* __restrict__ bbase, int* __restrict__ off, int n) {
    __shared__ int s[256];
    int t = threadIdx.x;
    int i = blockIdx.x * 256 + t;
    int v = (i < n) ? cur[i] : 0;
    s[t] = v;
    __syncthreads();
    for (int d = 1; d < 256; d <<= 1) {
        int x = (t >= d) ? s[t - d] : 0;
        __syncthreads();
        s[t] += x;
        __syncthreads();
    }
    int excl = s[t] - v;
    if (i < n) {
        int val = bbase[blockIdx.x] + excl;
        off[i] = val;
        cur[i] = val;
    }
}

// scatter packed (src:16b | ew_bf16:16b) into CSR slots (requires N <= 65536)
__global__ void k_scatter(const int* __restrict__ ei, const void* __restrict__ ew,
                          int* __restrict__ cur, unsigned int* __restrict__ edata, int E,
                          const int* __restrict__ flags) {
    int i = blockIdx.x * 256 + threadIdx.x;
    if (i >= E) return;
    int f64 = flags[1];
    int d = ld_dst(ei, i, E, f64);
    int s = f64 ? ei[2 * i] : ei[i];
    float w = rdf(ew, i, flags[0]);
    int pos = atomicAdd(&cur[d], 1);
    edata[pos] = (unsigned int)(s & 0xffff) | ((unsigned int)f2b(w) << 16);
}

// MFMA bf16 GEMM: H[n][j] = sum_k X[n][k]*W[k][j]; X bf16 [N][128], Wt bf16 [j][k].
// 64 nodes/block, 4 waves; H out bf16.
__global__ __launch_bounds__(256) void k_gemm(const unsigned short* __restrict__ Xb,
                                              const unsigned short* __restrict__ Wt,
                                              unsigned short* __restrict__ Hb, int N) {
    __shared__ unsigned char lds[49152];   // xs 16KB (64x128 bf16) + wt 32KB (128x128 bf16)
    unsigned char* xs = lds;
    unsigned char* wt = lds + 16384;
    int t = threadIdx.x;
    int node0 = blockIdx.x * 64;

    // stage Wt -> LDS (XOR-swizzled 16B chunks)
#pragma unroll
    for (int it = 0; it < 8; ++it) {
        int c = t + it * 256;
        int row = c >> 4, cc = c & 15;
        uint4 v = *(const uint4*)(Wt + row * 128 + cc * 8);
        int off = (row * 256 + cc * 16) ^ ((row & 7) << 4);
        *(uint4*)(wt + off) = v;
    }
    // stage X rows (already bf16) -> LDS, same swizzle
#pragma unroll
    for (int it = 0; it < 4; ++it) {
        int c = t + it * 256;
        int row = c >> 4, cc = c & 15;
        int g = node0 + row;
        uint4 v = make_uint4(0, 0, 0, 0);
        if (g < N) v = *(const uint4*)(Xb + (size_t)g * 128 + cc * 8);
        int off = (row * 256 + cc * 16) ^ ((row & 7) << 4);
        *(uint4*)(xs + off) = v;
    }
    __syncthreads();

    int w = t >> 6, l = t & 63;
    int arow = l & 15;
    int apart = l >> 4;
    f32x4 acc[8];
#pragma unroll
    for (int ct = 0; ct < 8; ++ct) acc[ct] = (f32x4){0.f, 0.f, 0.f, 0.f};

#pragma unroll
    for (int ks = 0; ks < 4; ++ks) {
        int grow = w * 16 + arow;
        int aoff = (grow * 256 + ks * 64 + apart * 16) ^ ((grow & 7) << 4);
        s16x8 afrag = *(const s16x8*)(xs + aoff);
#pragma unroll
        for (int ct = 0; ct < 8; ++ct) {
            int brow = ct * 16 + arow;
            int boff = (brow * 256 + ks * 64 + apart * 16) ^ ((brow & 7) << 4);
            s16x8 bfrag = *(const s16x8*)(wt + boff);
            acc[ct] = __builtin_amdgcn_mfma_f32_16x16x32_bf16(afrag, bfrag, acc[ct], 0, 0, 0);
        }
    }
    int orow0 = node0 + w * 16 + apart * 4;
    int ocol = arow;
#pragma unroll
    for (int ct = 0; ct < 8; ++ct) {
#pragma unroll
        for (int r = 0; r < 4; ++r) {
            int g = orow0 + r;
            if (g < N) Hb[(size_t)g * 128 + ct * 16 + ocol] = f2b(acc[ct][r]);
        }
    }
}

// fused: out = relu(LN(bias + sum_e ew*H[src])); one wave per node.
// lane l owns features 2l, 2l+1 (one uint = 2 bf16 per edge-row read).
template <bool FINAL>
__global__ __launch_bounds__(256) void k_agg_ln(const unsigned short* __restrict__ Hb,
                                                const unsigned int* __restrict__ edata,
                                                const int* __restrict__ off,
                                                const float* __restrict__ bias,
                                                const float* __restrict__ g,
                                                const float* __restrict__ be,
                                                unsigned short* __restrict__ outb,
                                                void* __restrict__ outAny,
                                                const int* __restrict__ flags, int N) {
    int wid = threadIdx.x >> 6;
    int l = threadIdx.x & 63;
    int node = blockIdx.x * 4 + wid;
    if (node >= N) return;
    float2 bv = *(const float2*)(bias + 2 * l);
    float a0 = bv.x, a1 = bv.y;
    int idx = off[node], end = off[node + 1];
    for (; idx + 3 < end; idx += 4) {
        unsigned int e0 = edata[idx], e1 = edata[idx + 1];
        unsigned int e2 = edata[idx + 2], e3 = edata[idx + 3];
        unsigned int v0 = ((const unsigned int*)(Hb + (size_t)(e0 & 0xffff) * 128))[l];
        unsigned int v1 = ((const unsigned int*)(Hb + (size_t)(e1 & 0xffff) * 128))[l];
        unsigned int v2 = ((const unsigned int*)(Hb + (size_t)(e2 & 0xffff) * 128))[l];
        unsigned int v3 = ((const unsigned int*)(Hb + (size_t)(e3 & 0xffff) * 128))[l];
        float w0 = b2f((unsigned short)(e0 >> 16)), w1 = b2f((unsigned short)(e1 >> 16));
        float w2 = b2f((unsigned short)(e2 >> 16)), w3 = b2f((unsigned short)(e3 >> 16));
        a0 += w0 * b2f((unsigned short)v0);  a1 += w0 * b2f((unsigned short)(v0 >> 16));
        a0 += w1 * b2f((unsigned short)v1);  a1 += w1 * b2f((unsigned short)(v1 >> 16));
        a0 += w2 * b2f((unsigned short)v2);  a1 += w2 * b2f((unsigned short)(v2 >> 16));
        a0 += w3 * b2f((unsigned short)v3);  a1 += w3 * b2f((unsigned short)(v3 >> 16));
    }
    for (; idx < end; ++idx) {
        unsigned int e = edata[idx];
        unsigned int v = ((const unsigned int*)(Hb + (size_t)(e & 0xffff) * 128))[l];
        float w = b2f((unsigned short)(e >> 16));
        a0 += w * b2f((unsigned short)v);
        a1 += w * b2f((unsigned short)(v >> 16));
    }
    // LayerNorm over 128 features spread as (2l, 2l+1) across 64 lanes
    float s = a0 + a1;
#pragma unroll
    for (int m = 32; m >= 1; m >>= 1) s += __shfl_xor(s, m, 64);
    float mu = s * (1.f / 128.f);
    float d0 = a0 - mu, d1 = a1 - mu;
    float q = d0 * d0 + d1 * d1;
#pragma unroll
    for (int m = 32; m >= 1; m >>= 1) q += __shfl_xor(q, m, 64);
    float rs = rsqrtf(q * (1.f / 128.f) + LN_EPS);
    float2 gv = *(const float2*)(g + 2 * l);
    float2 bev = *(const float2*)(be + 2 * l);
    float r0 = fmaxf(d0 * rs * gv.x + bev.x, 0.f);
    float r1 = fmaxf(d1 * rs * gv.y + bev.y, 0.f);
    if (FINAL) {
        if (flags[0]) {
            ((float2*)outAny)[(size_t)node * 64 + l] = make_float2(r0, r1);
        } else {
            ((unsigned int*)outAny)[(size_t)node * 64 + l] = pk2(r0, r1);
        }
    } else {
        ((unsigned int*)outb)[(size_t)node * 64 + l] = pk2(r0, r1);
    }
}

extern "C" void kernel_launch(void* const* d_in, const int* in_sizes, int n_in,
                              void* d_out, int out_size, void* d_ws, size_t ws_size,
                              hipStream_t stream) {
    const unsigned short* x_u16 = (const unsigned short*)d_in[0];
    const int*            ei    = (const int*)d_in[1];

    const int N = in_sizes[0] / 128;
    const int E = in_sizes[2];

    // ---- workspace layout ----
    unsigned short* Xb = (unsigned short*)d_ws;          // N*128 bf16 (also mid-layer act)
    unsigned short* Hb = Xb + (size_t)N * 128;           // N*128 bf16
    unsigned int* edata = (unsigned int*)(Hb + (size_t)N * 128); // E packed
    int* off    = (int*)(edata + E);                     // N+1 (+pad)
    int* cur    = off + (N + 4);                         // N
    int* bsum   = cur + N;                               // 256
    int* bbase  = bsum + 256;                            // 256
    int* flags  = bbase + 256;                           // 8
    unsigned short* Wt1 = (unsigned short*)(flags + 8);  // 16384 bf16
    unsigned short* Wt2 = Wt1 + 16384;                   // 16384 bf16
    float* sm   = (float*)(Wt2 + 16384);                 // 6*128 f32
    float* b1f  = sm;
    float* b2f_ = sm + 128;
    float* g1f  = sm + 256;
    float* g2f  = sm + 384;
    float* be1f = sm + 512;
    float* be2f = sm + 640;

    const int nb = (N + 255) / 256;
    const int eb = (E + 255) / 256;
    const int nodeBlocks = (N + 3) / 4;
    const int gemmBlocks = (N + 63) / 64;

    k_detect<<<1, 256, 0, stream>>>(x_u16, ei, E, flags);
    k_prep<<<64, 256, 0, stream>>>(d_in[3], d_in[5], d_in[4], d_in[6],
                                   d_in[7], d_in[9], d_in[8], d_in[10],
                                   Wt1, Wt2, sm, flags);
    k_cvt_x<<<(N * 128 / 4 + 255) / 256, 256, 0, stream>>>(d_in[0], Xb, N * 128 / 4, flags);

    k_zero_i32<<<nb, 256, 0, stream>>>(cur, N);
    k_hist<<<eb, 256, 0, stream>>>(ei, cur, E, flags);
    k_blocksum<<<nb, 256, 0, stream>>>(cur, bsum, N);
    k_scan_bsum<<<1, 256, 0, stream>>>(bsum, bbase, off, nb, N);
    k_scan_tiles<<<nb, 256, 0, stream>>>(cur, bbase, off, N);
    k_scatter<<<eb, 256, 0, stream>>>(ei, d_in[2], cur, edata, E, flags);

    // layer 1
    k_gemm<<<gemmBlocks, 256, 0, stream>>>(Xb, Wt1, Hb, N);
    k_agg_ln<false><<<nodeBlocks, 256, 0, stream>>>(Hb, edata, off, b1f, g1f, be1f, Xb, nullptr, flags, N);

    // layer 2
    k_gemm<<<gemmBlocks, 256, 0, stream>>>(Xb, Wt2, Hb, N);
    k_agg_ln<true><<<nodeBlocks, 256, 0, stream>>>(Hb, edata, off, b2f_, g2f, be2f, nullptr, d_out, flags, N);
}

// Round 5
// 192.434 us; speedup vs baseline: 2.8525x; 1.1343x over previous
//
#include <hip/hip_runtime.h>
#include <stdint.h>

#define LN_EPS 1e-5f
#define G1 256
#define P1CAP 4096
#define P3CAP 6144

typedef __attribute__((ext_vector_type(8))) short s16x8;
typedef __attribute__((ext_vector_type(4))) float f32x4;

__device__ __forceinline__ float b2f(unsigned short u) {
    union { unsigned int i; float f; } v; v.i = ((unsigned int)u) << 16; return v.f;
}
__device__ __forceinline__ unsigned short f2b(float f) {
    union { float f; unsigned int i; } v; v.f = f;
    unsigned int u = v.i;
    return (unsigned short)((u + 0x7fffu + ((u >> 16) & 1u)) >> 16);
}
__device__ __forceinline__ unsigned int pk2(float a, float b) {
    return (unsigned int)f2b(a) | ((unsigned int)f2b(b) << 16);
}

// flags[0] = floats are f32 (else bf16); flags[1] = edge_index is int64 (else int32)
__global__ void k_detect(const unsigned short* __restrict__ xu,
                         const int* __restrict__ ei, int E, int* __restrict__ flags) {
    __shared__ int s[2];
    int t = threadIdx.x;
    if (t < 2) s[t] = 0;
    __syncthreads();
    int c1 = 0;
    for (int i = t; i < 2048; i += 256)
        if (fabsf(b2f(xu[i])) > 1e6f) ++c1;
    if (c1) atomicAdd(&s[0], c1);
    int mn = (E < 1024) ? E : 1024;
    int z = 0;
    for (int i = t; i < mn; i += 256)
        if (ei[2 * i + 1] == 0) ++z;
    if (z) atomicAdd(&s[1], z);
    __syncthreads();
    if (t == 0) {
        flags[0] = (s[0] > 32) ? 1 : 0;
        flags[1] = (s[1] > (mn >> 1)) ? 1 : 0;
    }
}

__device__ __forceinline__ float rdf(const void* p, int i, int f32flag) {
    return f32flag ? ((const float*)p)[i] : b2f(((const unsigned short*)p)[i]);
}

// 64 blocks: W1,W2 -> transposed bf16 Wt[j][k]; block 0 also converts small params
__global__ void k_prep(const void* W1, const void* W2,
                       const void* b1, const void* b2,
                       const void* g1, const void* g2,
                       const void* be1, const void* be2,
                       unsigned short* __restrict__ Wt1, unsigned short* __restrict__ Wt2,
                       float* __restrict__ sm, const int* __restrict__ flags) {
    int t = threadIdx.x;
    int f = flags[0];
    int i = blockIdx.x * 256 + t;  // 64*256 = 16384
    int k = i >> 7, j = i & 127;
    Wt1[j * 128 + k] = f2b(rdf(W1, i, f));
    Wt2[j * 128 + k] = f2b(rdf(W2, i, f));
    if (blockIdx.x == 0 && t < 128) {
        sm[t]       = rdf(b1, t, f);
        sm[128 + t] = rdf(b2, t, f);
        sm[256 + t] = rdf(g1, t, f);
        sm[384 + t] = rdf(g2, t, f);
        sm[512 + t] = rdf(be1, t, f);
        sm[640 + t] = rdf(be2, t, f);
    }
}

// pass 1: per-block LDS binning by bucket (dst>>8); coalesced block-segment writeout
__global__ __launch_bounds__(256) void k_p1(const int* __restrict__ ei, const void* __restrict__ ew,
                                            int E, int B, int chunk,
                                            const int* __restrict__ flags,
                                            unsigned int* __restrict__ gA,
                                            unsigned char* __restrict__ g8,
                                            int* __restrict__ cnt2d, int* __restrict__ lofs2d) {
    __shared__ int hist[256], cur[256], tmp[256];
    __shared__ unsigned int bin32[P1CAP];
    __shared__ unsigned char bin8[P1CAP];
    int t = threadIdx.x, g = blockIdx.x;
    int base = g * chunk;
    int cnt = E - base; if (cnt > chunk) cnt = chunk; if (cnt < 0) cnt = 0;
    int f64 = flags[1], f32f = flags[0];
    hist[t] = 0;
    __syncthreads();
    for (int i = t; i < cnt; i += 256) {
        int e = base + i;
        int d = f64 ? ei[2 * E + 2 * e] : ei[E + e];
        atomicAdd(&hist[d >> 8], 1);
    }
    __syncthreads();
    int v = hist[t];
    tmp[t] = v;
    __syncthreads();
    for (int d = 1; d < 256; d <<= 1) {
        int x = (t >= d) ? tmp[t - d] : 0;
        __syncthreads();
        tmp[t] += x;
        __syncthreads();
    }
    int excl = tmp[t] - v;
    cur[t] = excl;
    if (t < B) { cnt2d[t * G1 + g] = v; lofs2d[t * G1 + g] = excl; }
    __syncthreads();
    for (int i = t; i < cnt; i += 256) {
        int e = base + i;
        int d, sN;
        if (f64) { d = ei[2 * E + 2 * e]; sN = ei[2 * e]; }
        else     { d = ei[E + e];         sN = ei[e]; }
        float w = f32f ? ((const float*)ew)[e] : b2f(((const unsigned short*)ew)[e]);
        int p = atomicAdd(&cur[d >> 8], 1);
        bin32[p] = (unsigned int)(sN & 0xffff) | ((unsigned int)f2b(w) << 16);
        bin8[p]  = (unsigned char)(d & 255);
    }
    __syncthreads();
    for (int j = t; j < cnt; j += 256) {
        gA[base + j] = bin32[j];
        g8[base + j] = bin8[j];
    }
}

// pass 1.5a: bucket totals + exclusive scan -> bb[]; one block
__global__ void k_p15a(const int* __restrict__ cnt2d, int* __restrict__ bb, int B) {
    __shared__ int tmp[256];
    int t = threadIdx.x;
    int s = 0;
    if (t < B) {
        const int* r = cnt2d + t * G1;
        for (int g = 0; g < G1; ++g) s += r[g];
    }
    int v = s;
    tmp[t] = v;
    __syncthreads();
    for (int d = 1; d < 256; d <<= 1) {
        int x = (t >= d) ? tmp[t - d] : 0;
        __syncthreads();
        tmp[t] += x;
        __syncthreads();
    }
    if (t < B) bb[t] = tmp[t] - v;
    if (t == 255) bb[B] = tmp[255];
}

// pass 1.5b: per-bucket exclusive scan over blocks -> pos2d
__global__ void k_p15b(const int* __restrict__ cnt2d, const int* __restrict__ bb,
                       int* __restrict__ pos2d) {
    __shared__ int tmp[256];
    int b = blockIdx.x, t = threadIdx.x;
    int v = cnt2d[b * G1 + t];
    tmp[t] = v;
    __syncthreads();
    for (int d = 1; d < 256; d <<= 1) {
        int x = (t >= d) ? tmp[t - d] : 0;
        __syncthreads();
        tmp[t] += x;
        __syncthreads();
    }
    pos2d[b * G1 + t] = bb[b] + tmp[t] - v;
}

// pass 2: permute block-major -> bucket-major (coalesced-ish runs)
__global__ __launch_bounds__(256) void k_p2(const unsigned int* __restrict__ gA,
                                            const unsigned char* __restrict__ g8,
                                            const int* __restrict__ cnt2d,
                                            const int* __restrict__ lofs2d,
                                            const int* __restrict__ pos2d,
                                            unsigned int* __restrict__ eb32,
                                            unsigned char* __restrict__ eb8,
                                            int B, int chunk) {
    int g = blockIdx.x;
    int wid = threadIdx.x >> 6, l = threadIdx.x & 63;
    for (int b = wid; b < B; b += 4) {
        int c = cnt2d[b * G1 + g];
        int sb = g * chunk + lofs2d[b * G1 + g];
        int db = pos2d[b * G1 + g];
        for (int j = l; j < c; j += 64) {
            eb32[db + j] = gA[sb + j];
            eb8[db + j]  = g8[sb + j];
        }
    }
}

// pass 3: within-bucket sort by exact dst (all in LDS) + off[] writeout
__global__ __launch_bounds__(256) void k_p3(const unsigned int* __restrict__ eb32,
                                            const unsigned char* __restrict__ eb8,
                                            const int* __restrict__ bb,
                                            unsigned int* __restrict__ edata,
                                            int* __restrict__ off, int N, int B) {
    __shared__ unsigned int raw[P3CAP];
    __shared__ unsigned int srt[P3CAP];
    __shared__ unsigned char r8[P3CAP];
    __shared__ int h[256], tmp[256];
    int b = blockIdx.x, t = threadIdx.x;
    int base = bb[b], cnt = bb[b + 1] - base;
    int node0 = b << 8;
    int nn = N - node0; if (nn > 256) nn = 256;
    h[t] = 0;
    for (int i = t; i < cnt; i += 256) { raw[i] = eb32[base + i]; r8[i] = eb8[base + i]; }
    __syncthreads();
    for (int i = t; i < cnt; i += 256) atomicAdd(&h[r8[i]], 1);
    __syncthreads();
    int v = h[t];
    tmp[t] = v;
    __syncthreads();
    for (int d = 1; d < 256; d <<= 1) {
        int x = (t >= d) ? tmp[t - d] : 0;
        __syncthreads();
        tmp[t] += x;
        __syncthreads();
    }
    int excl = tmp[t] - v;
    if (t < nn) off[node0 + t] = base + excl;
    if (b == B - 1 && t == 0) off[N] = base + cnt;
    h[t] = excl;  // cursor
    __syncthreads();
    for (int i = t; i < cnt; i += 256) {
        int p = atomicAdd(&h[r8[i]], 1);
        srt[p] = raw[i];
    }
    __syncthreads();
    for (int i = t; i < cnt; i += 256) edata[base + i] = srt[i];
}

// MFMA bf16 GEMM: H[n][j] = sum_k X[n][k]*W[k][j]; Wt bf16 [j][k] (transposed).
// layer1: X is d_in[0] (f32 or bf16 per flags[0]); else X is bf16 workspace.
__global__ __launch_bounds__(256) void k_gemm(const void* __restrict__ X,
                                              const unsigned short* __restrict__ Wt,
                                              unsigned short* __restrict__ Hb, int N,
                                              const int* __restrict__ flags, int layer1) {
    __shared__ unsigned char lds[49152];   // xs 16KB (64x128 bf16) + wt 32KB (128x128 bf16)
    unsigned char* xs = lds;
    unsigned char* wt = lds + 16384;
    int t = threadIdx.x;
    int node0 = blockIdx.x * 64;
    int f32in = layer1 ? flags[0] : 0;

#pragma unroll
    for (int it = 0; it < 8; ++it) {
        int c = t + it * 256;
        int row = c >> 4, cc = c & 15;
        uint4 v = *(const uint4*)(Wt + row * 128 + cc * 8);
        int off = (row * 256 + cc * 16) ^ ((row & 7) << 4);
        *(uint4*)(wt + off) = v;
    }
#pragma unroll
    for (int it = 0; it < 4; ++it) {
        int c = t + it * 256;
        int row = c >> 4, cc = c & 15;
        int g = node0 + row;
        uint4 v = make_uint4(0, 0, 0, 0);
        if (g < N) {
            if (f32in) {
                const float* xr = (const float*)X + (size_t)g * 128 + cc * 8;
                float4 f0 = *(const float4*)xr;
                float4 f1 = *(const float4*)(xr + 4);
                v.x = pk2(f0.x, f0.y); v.y = pk2(f0.z, f0.w);
                v.z = pk2(f1.x, f1.y); v.w = pk2(f1.z, f1.w);
            } else {
                v = *(const uint4*)((const unsigned short*)X + (size_t)g * 128 + cc * 8);
            }
        }
        int off = (row * 256 + cc * 16) ^ ((row & 7) << 4);
        *(uint4*)(xs + off) = v;
    }
    __syncthreads();

    int w = t >> 6, l = t & 63;
    int arow = l & 15;
    int apart = l >> 4;
    f32x4 acc[8];
#pragma unroll
    for (int ct = 0; ct < 8; ++ct) acc[ct] = (f32x4){0.f, 0.f, 0.f, 0.f};

#pragma unroll
    for (int ks = 0; ks < 4; ++ks) {
        int grow = w * 16 + arow;
        int aoff = (grow * 256 + ks * 64 + apart * 16) ^ ((grow & 7) << 4);
        s16x8 afrag = *(const s16x8*)(xs + aoff);
#pragma unroll
        for (int ct = 0; ct < 8; ++ct) {
            int brow = ct * 16 + arow;
            int boff = (brow * 256 + ks * 64 + apart * 16) ^ ((brow & 7) << 4);
            s16x8 bfrag = *(const s16x8*)(wt + boff);
            acc[ct] = __builtin_amdgcn_mfma_f32_16x16x32_bf16(afrag, bfrag, acc[ct], 0, 0, 0);
        }
    }
    int orow0 = node0 + w * 16 + apart * 4;
    int ocol = arow;
#pragma unroll
    for (int ct = 0; ct < 8; ++ct) {
#pragma unroll
        for (int r = 0; r < 4; ++r) {
            int g = orow0 + r;
            if (g < N) Hb[(size_t)g * 128 + ct * 16 + ocol] = f2b(acc[ct][r]);
        }
    }
}

// fused: out = relu(LN(bias + sum_e ew*H[src])); one wave per node.
// lane l owns features 2l, 2l+1.
template <bool FINAL>
__global__ __launch_bounds__(256) void k_agg_ln(const unsigned short* __restrict__ Hb,
                                                const unsigned int* __restrict__ edata,
                                                const int* __restrict__ off,
                                                const float* __restrict__ bias,
                                                const float* __restrict__ g,
                                                const float* __restrict__ be,
                                                unsigned short* __restrict__ outb,
                                                void* __restrict__ outAny,
                                                const int* __restrict__ flags, int N) {
    int wid = threadIdx.x >> 6;
    int l = threadIdx.x & 63;
    int node = blockIdx.x * 4 + wid;
    if (node >= N) return;
    float2 bv = *(const float2*)(bias + 2 * l);
    float a0 = bv.x, a1 = bv.y;
    int idx = off[node], end = off[node + 1];
    for (; idx + 3 < end; idx += 4) {
        unsigned int e0 = edata[idx], e1 = edata[idx + 1];
        unsigned int e2 = edata[idx + 2], e3 = edata[idx + 3];
        unsigned int v0 = ((const unsigned int*)(Hb + (size_t)(e0 & 0xffff) * 128))[l];
        unsigned int v1 = ((const unsigned int*)(Hb + (size_t)(e1 & 0xffff) * 128))[l];
        unsigned int v2 = ((const unsigned int*)(Hb + (size_t)(e2 & 0xffff) * 128))[l];
        unsigned int v3 = ((const unsigned int*)(Hb + (size_t)(e3 & 0xffff) * 128))[l];
        float w0 = b2f((unsigned short)(e0 >> 16)), w1 = b2f((unsigned short)(e1 >> 16));
        float w2 = b2f((unsigned short)(e2 >> 16)), w3 = b2f((unsigned short)(e3 >> 16));
        a0 += w0 * b2f((unsigned short)v0);  a1 += w0 * b2f((unsigned short)(v0 >> 16));
        a0 += w1 * b2f((unsigned short)v1);  a1 += w1 * b2f((unsigned short)(v1 >> 16));
        a0 += w2 * b2f((unsigned short)v2);  a1 += w2 * b2f((unsigned short)(v2 >> 16));
        a0 += w3 * b2f((unsigned short)v3);  a1 += w3 * b2f((unsigned short)(v3 >> 16));
    }
    for (; idx < end; ++idx) {
        unsigned int e = edata[idx];
        unsigned int v = ((const unsigned int*)(Hb + (size_t)(e & 0xffff) * 128))[l];
        float w = b2f((unsigned short)(e >> 16));
        a0 += w * b2f((unsigned short)v);
        a1 += w * b2f((unsigned short)(v >> 16));
    }
    float s = a0 + a1;
#pragma unroll
    for (int m = 32; m >= 1; m >>= 1) s += __shfl_xor(s, m, 64);
    float mu = s * (1.f / 128.f);
    float d0 = a0 - mu, d1 = a1 - mu;
    float q = d0 * d0 + d1 * d1;
#pragma unroll
    for (int m = 32; m >= 1; m >>= 1) q += __shfl_xor(q, m, 64);
    float rs = rsqrtf(q * (1.f / 128.f) + LN_EPS);
    float2 gv = *(const float2*)(g + 2 * l);
    float2 bev = *(const float2*)(be + 2 * l);
    float r0 = fmaxf(d0 * rs * gv.x + bev.x, 0.f);
    float r1 = fmaxf(d1 * rs * gv.y + bev.y, 0.f);
    if (FINAL) {
        if (flags[0]) {
            ((float2*)outAny)[(size_t)node * 64 + l] = make_float2(r0, r1);
        } else {
            ((unsigned int*)outAny)[(size_t)node * 64 + l] = pk2(r0, r1);
        }
    } else {
        ((unsigned int*)outb)[(size_t)node * 64 + l] = pk2(r0, r1);
    }
}

extern "C" void kernel_launch(void* const* d_in, const int* in_sizes, int n_in,
                              void* d_out, int out_size, void* d_ws, size_t ws_size,
                              hipStream_t stream) {
    const unsigned short* x_u16 = (const unsigned short*)d_in[0];
    const int*            ei    = (const int*)d_in[1];

    const int N = in_sizes[0] / 128;
    const int E = in_sizes[2];
    const int B = (N + 255) >> 8;          // buckets of 256 nodes (<=256)
    const int chunk = (E + G1 - 1) / G1;

    // ---- workspace layout ----
    unsigned short* Xb = (unsigned short*)d_ws;            // N*128 bf16 (mid act)
    unsigned short* Hb = Xb + (size_t)N * 128;             // N*128 bf16
    unsigned int* gA    = (unsigned int*)(Hb + (size_t)N * 128); // E
    unsigned int* eb32  = gA + E;                          // E
    unsigned int* edata = eb32 + E;                        // E
    unsigned char* g8   = (unsigned char*)(edata + E);     // E (pad 4)
    unsigned char* eb8  = g8 + ((E + 3) & ~3);             // E (pad 4)
    int* cnt2d  = (int*)(eb8 + ((E + 3) & ~3));            // 256*256
    int* lofs2d = cnt2d + 65536;                           // 256*256
    int* pos2d  = lofs2d + 65536;                          // 256*256
    int* bb     = pos2d + 65536;                           // B+1 (+pad)
    int* off    = bb + 260;                                // N+1 (+pad)
    int* flags  = off + N + 4;                             // 8
    unsigned short* Wt1 = (unsigned short*)(flags + 8);    // 16384 bf16
    unsigned short* Wt2 = Wt1 + 16384;                     // 16384 bf16
    float* sm   = (float*)(Wt2 + 16384);                   // 6*128 f32
    float* b1f  = sm;
    float* b2f_ = sm + 128;
    float* g1f  = sm + 256;
    float* g2f  = sm + 384;
    float* be1f = sm + 512;
    float* be2f = sm + 640;

    const int nodeBlocks = (N + 3) / 4;
    const int gemmBlocks = (N + 63) / 64;

    k_detect<<<1, 256, 0, stream>>>(x_u16, ei, E, flags);
    k_prep<<<64, 256, 0, stream>>>(d_in[3], d_in[5], d_in[4], d_in[6],
                                   d_in[7], d_in[9], d_in[8], d_in[10],
                                   Wt1, Wt2, sm, flags);

    // ---- CSR build: 3-pass counting sort, coalesced writes ----
    k_p1<<<G1, 256, 0, stream>>>(ei, d_in[2], E, B, chunk, flags, gA, g8, cnt2d, lofs2d);
    k_p15a<<<1, 256, 0, stream>>>(cnt2d, bb, B);
    k_p15b<<<B, 256, 0, stream>>>(cnt2d, bb, pos2d);
    k_p2<<<G1, 256, 0, stream>>>(gA, g8, cnt2d, lofs2d, pos2d, eb32, eb8, B, chunk);
    k_p3<<<B, 256, 0, stream>>>(eb32, eb8, bb, edata, off, N, B);

    // ---- layer 1 (GEMM reads d_in[0] directly, converts in staging) ----
    k_gemm<<<gemmBlocks, 256, 0, stream>>>(d_in[0], Wt1, Hb, N, flags, 1);
    k_agg_ln<false><<<nodeBlocks, 256, 0, stream>>>(Hb, edata, off, b1f, g1f, be1f, Xb, nullptr, flags, N);

    // ---- layer 2 ----
    k_gemm<<<gemmBlocks, 256, 0, stream>>>(Xb, Wt2, Hb, N, flags, 0);
    k_agg_ln<true><<<nodeBlocks, 256, 0, stream>>>(Hb, edata, off, b2f_, g2f, be2f, nullptr, d_out, flags, N);
}

// Round 6
// 153.114 us; speedup vs baseline: 3.5850x; 1.2568x over previous
//
#include <hip/hip_runtime.h>
#include <stdint.h>

#define LN_EPS 1e-5f
#define G1 256
#define P1CAP 4096
#define P3CAP 6144

typedef __attribute__((ext_vector_type(8))) short s16x8;
typedef __attribute__((ext_vector_type(4))) float f32x4;

__device__ __forceinline__ float b2f(unsigned short u) {
    union { unsigned int i; float f; } v; v.i = ((unsigned int)u) << 16; return v.f;
}
__device__ __forceinline__ unsigned short f2b(float f) {
    union { float f; unsigned int i; } v; v.f = f;
    unsigned int u = v.i;
    return (unsigned short)((u + 0x7fffu + ((u >> 16) & 1u)) >> 16);
}
__device__ __forceinline__ unsigned int pk2(float a, float b) {
    return (unsigned int)f2b(a) | ((unsigned int)f2b(b) << 16);
}

// flags[0] = floats are f32 (else bf16); flags[1] = edge_index is int64 (else int32)
__global__ void k_detect(const unsigned short* __restrict__ xu,
                         const int* __restrict__ ei, int E, int* __restrict__ flags) {
    __shared__ int s[2];
    int t = threadIdx.x;
    if (t < 2) s[t] = 0;
    __syncthreads();
    int c1 = 0;
    for (int i = t; i < 2048; i += 256)
        if (fabsf(b2f(xu[i])) > 1e6f) ++c1;
    if (c1) atomicAdd(&s[0], c1);
    int mn = (E < 1024) ? E : 1024;
    int z = 0;
    for (int i = t; i < mn; i += 256)
        if (ei[2 * i + 1] == 0) ++z;
    if (z) atomicAdd(&s[1], z);
    __syncthreads();
    if (t == 0) {
        flags[0] = (s[0] > 32) ? 1 : 0;
        flags[1] = (s[1] > (mn >> 1)) ? 1 : 0;
    }
}

__device__ __forceinline__ float rdf(const void* p, int i, int f32flag) {
    return f32flag ? ((const float*)p)[i] : b2f(((const unsigned short*)p)[i]);
}

// 64 blocks: W1,W2 -> transposed bf16 Wt[j][k]; block 0 also converts small params
__global__ void k_prep(const void* W1, const void* W2,
                       const void* b1, const void* b2,
                       const void* g1, const void* g2,
                       const void* be1, const void* be2,
                       unsigned short* __restrict__ Wt1, unsigned short* __restrict__ Wt2,
                       float* __restrict__ sm, const int* __restrict__ flags) {
    int t = threadIdx.x;
    int f = flags[0];
    int i = blockIdx.x * 256 + t;  // 64*256 = 16384
    int k = i >> 7, j = i & 127;
    Wt1[j * 128 + k] = f2b(rdf(W1, i, f));
    Wt2[j * 128 + k] = f2b(rdf(W2, i, f));
    if (blockIdx.x == 0 && t < 128) {
        sm[t]       = rdf(b1, t, f);
        sm[128 + t] = rdf(b2, t, f);
        sm[256 + t] = rdf(g1, t, f);
        sm[384 + t] = rdf(g2, t, f);
        sm[512 + t] = rdf(be1, t, f);
        sm[640 + t] = rdf(be2, t, f);
    }
}

// pass 1: per-block LDS binning by bucket (dst>>8); coalesced block-segment writeout
__global__ __launch_bounds__(256) void k_p1(const int* __restrict__ ei, const void* __restrict__ ew,
                                            int E, int B, int chunk,
                                            const int* __restrict__ flags,
                                            unsigned int* __restrict__ gA,
                                            unsigned char* __restrict__ g8,
                                            int* __restrict__ cnt2d, int* __restrict__ lofs2d) {
    __shared__ int hist[256], cur[256], tmp[256];
    __shared__ unsigned int bin32[P1CAP];
    __shared__ unsigned char bin8[P1CAP];
    int t = threadIdx.x, g = blockIdx.x;
    int base = g * chunk;
    int cnt = E - base; if (cnt > chunk) cnt = chunk; if (cnt < 0) cnt = 0;
    int f64 = flags[1], f32f = flags[0];
    hist[t] = 0;
    __syncthreads();
    for (int i = t; i < cnt; i += 256) {
        int e = base + i;
        int d = f64 ? ei[2 * E + 2 * e] : ei[E + e];
        atomicAdd(&hist[d >> 8], 1);
    }
    __syncthreads();
    int v = hist[t];
    tmp[t] = v;
    __syncthreads();
    for (int d = 1; d < 256; d <<= 1) {
        int x = (t >= d) ? tmp[t - d] : 0;
        __syncthreads();
        tmp[t] += x;
        __syncthreads();
    }
    int excl = tmp[t] - v;
    cur[t] = excl;
    if (t < B) { cnt2d[t * G1 + g] = v; lofs2d[t * G1 + g] = excl; }
    __syncthreads();
    for (int i = t; i < cnt; i += 256) {
        int e = base + i;
        int d, sN;
        if (f64) { d = ei[2 * E + 2 * e]; sN = ei[2 * e]; }
        else     { d = ei[E + e];         sN = ei[e]; }
        float w = f32f ? ((const float*)ew)[e] : b2f(((const unsigned short*)ew)[e]);
        int p = atomicAdd(&cur[d >> 8], 1);
        bin32[p] = (unsigned int)(sN & 0xffff) | ((unsigned int)f2b(w) << 16);
        bin8[p]  = (unsigned char)(d & 255);
    }
    __syncthreads();
    for (int j = t; j < cnt; j += 256) {
        gA[base + j] = bin32[j];
        g8[base + j] = bin8[j];
    }
}

// pass 1.5a: bucket totals + exclusive scan -> bb[]; one block
__global__ void k_p15a(const int* __restrict__ cnt2d, int* __restrict__ bb, int B) {
    __shared__ int tmp[256];
    int t = threadIdx.x;
    int s = 0;
    if (t < B) {
        const int* r = cnt2d + t * G1;
        for (int g = 0; g < G1; ++g) s += r[g];
    }
    int v = s;
    tmp[t] = v;
    __syncthreads();
    for (int d = 1; d < 256; d <<= 1) {
        int x = (t >= d) ? tmp[t - d] : 0;
        __syncthreads();
        tmp[t] += x;
        __syncthreads();
    }
    if (t < B) bb[t] = tmp[t] - v;
    if (t == 255) bb[B] = tmp[255];
}

// pass 3: gather bucket's 256 block-segments from gA/g8 into LDS, sort by exact
// dst in LDS, write edata + off coalesced. (replaces old p15b+p2+p3)
__global__ __launch_bounds__(256) void k_p3(const unsigned int* __restrict__ gA,
                                            const unsigned char* __restrict__ g8,
                                            const int* __restrict__ cnt2d,
                                            const int* __restrict__ lofs2d,
                                            const int* __restrict__ bb,
                                            unsigned int* __restrict__ edata,
                                            int* __restrict__ off, int N, int B, int chunk) {
    __shared__ unsigned int raw[P3CAP];
    __shared__ unsigned int srt[P3CAP];
    __shared__ unsigned char r8[P3CAP];
    __shared__ int h[256], tmp[256];
    __shared__ int s_cnt;
    int b = blockIdx.x, t = threadIdx.x;
    // segment for source-block t
    int segc = cnt2d[b * G1 + t];
    int sbase = t * chunk + lofs2d[b * G1 + t];
    // scan segment lengths -> LDS offsets
    int v = segc;
    tmp[t] = v;
    __syncthreads();
    for (int d = 1; d < 256; d <<= 1) {
        int x = (t >= d) ? tmp[t - d] : 0;
        __syncthreads();
        tmp[t] += x;
        __syncthreads();
    }
    int lo = tmp[t] - v;
    if (t == 255) s_cnt = tmp[255];
    // gather my segment into LDS (serial ~E/65536 iters)
    for (int j = 0; j < segc; ++j) {
        raw[lo + j] = gA[sbase + j];
        r8[lo + j]  = g8[sbase + j];
    }
    h[t] = 0;
    __syncthreads();
    int cnt = s_cnt;
    int base = bb[b];
    int node0 = b << 8;
    int nn = N - node0; if (nn > 256) nn = 256;
    // histogram by exact dst low byte
    for (int i = t; i < cnt; i += 256) atomicAdd(&h[r8[i]], 1);
    __syncthreads();
    v = h[t];
    tmp[t] = v;
    __syncthreads();
    for (int d = 1; d < 256; d <<= 1) {
        int x = (t >= d) ? tmp[t - d] : 0;
        __syncthreads();
        tmp[t] += x;
        __syncthreads();
    }
    int excl = tmp[t] - v;
    if (t < nn) off[node0 + t] = base + excl;
    if (b == B - 1 && t == 0) off[N] = base + cnt;
    h[t] = excl;  // cursor
    __syncthreads();
    for (int i = t; i < cnt; i += 256) {
        int p = atomicAdd(&h[r8[i]], 1);
        srt[p] = raw[i];
    }
    __syncthreads();
    for (int i = t; i < cnt; i += 256) edata[base + i] = srt[i];
}

// MFMA bf16 GEMM: H[n][j] = sum_k X[n][k]*W[k][j]; Wt bf16 [j][k] (transposed).
// layer1: X is d_in[0] (f32 or bf16 per flags[0]); else X is bf16 workspace.
__global__ __launch_bounds__(256) void k_gemm(const void* __restrict__ X,
                                              const unsigned short* __restrict__ Wt,
                                              unsigned short* __restrict__ Hb, int N,
                                              const int* __restrict__ flags, int layer1) {
    __shared__ unsigned char lds[49152];   // xs 16KB (64x128 bf16) + wt 32KB (128x128 bf16)
    unsigned char* xs = lds;
    unsigned char* wt = lds + 16384;
    int t = threadIdx.x;
    int node0 = blockIdx.x * 64;
    int f32in = layer1 ? flags[0] : 0;

#pragma unroll
    for (int it = 0; it < 8; ++it) {
        int c = t + it * 256;
        int row = c >> 4, cc = c & 15;
        uint4 v = *(const uint4*)(Wt + row * 128 + cc * 8);
        int off = (row * 256 + cc * 16) ^ ((row & 7) << 4);
        *(uint4*)(wt + off) = v;
    }
#pragma unroll
    for (int it = 0; it < 4; ++it) {
        int c = t + it * 256;
        int row = c >> 4, cc = c & 15;
        int g = node0 + row;
        uint4 v = make_uint4(0, 0, 0, 0);
        if (g < N) {
            if (f32in) {
                const float* xr = (const float*)X + (size_t)g * 128 + cc * 8;
                float4 f0 = *(const float4*)xr;
                float4 f1 = *(const float4*)(xr + 4);
                v.x = pk2(f0.x, f0.y); v.y = pk2(f0.z, f0.w);
                v.z = pk2(f1.x, f1.y); v.w = pk2(f1.z, f1.w);
            } else {
                v = *(const uint4*)((const unsigned short*)X + (size_t)g * 128 + cc * 8);
            }
        }
        int off = (row * 256 + cc * 16) ^ ((row & 7) << 4);
        *(uint4*)(xs + off) = v;
    }
    __syncthreads();

    int w = t >> 6, l = t & 63;
    int arow = l & 15;
    int apart = l >> 4;
    f32x4 acc[8];
#pragma unroll
    for (int ct = 0; ct < 8; ++ct) acc[ct] = (f32x4){0.f, 0.f, 0.f, 0.f};

#pragma unroll
    for (int ks = 0; ks < 4; ++ks) {
        int grow = w * 16 + arow;
        int aoff = (grow * 256 + ks * 64 + apart * 16) ^ ((grow & 7) << 4);
        s16x8 afrag = *(const s16x8*)(xs + aoff);
#pragma unroll
        for (int ct = 0; ct < 8; ++ct) {
            int brow = ct * 16 + arow;
            int boff = (brow * 256 + ks * 64 + apart * 16) ^ ((brow & 7) << 4);
            s16x8 bfrag = *(const s16x8*)(wt + boff);
            acc[ct] = __builtin_amdgcn_mfma_f32_16x16x32_bf16(afrag, bfrag, acc[ct], 0, 0, 0);
        }
    }
    int orow0 = node0 + w * 16 + apart * 4;
    int ocol = arow;
#pragma unroll
    for (int ct = 0; ct < 8; ++ct) {
#pragma unroll
        for (int r = 0; r < 4; ++r) {
            int g = orow0 + r;
            if (g < N) Hb[(size_t)g * 128 + ct * 16 + ocol] = f2b(acc[ct][r]);
        }
    }
}

// fused: out = relu(LN(bias + sum_e ew*H[src])); one wave per node.
// lane l owns features 2l, 2l+1.
template <bool FINAL>
__global__ __launch_bounds__(256) void k_agg_ln(const unsigned short* __restrict__ Hb,
                                                const unsigned int* __restrict__ edata,
                                                const int* __restrict__ off,
                                                const float* __restrict__ bias,
                                                const float* __restrict__ g,
                                                const float* __restrict__ be,
                                                unsigned short* __restrict__ outb,
                                                void* __restrict__ outAny,
                                                const int* __restrict__ flags, int N) {
    int wid = threadIdx.x >> 6;
    int l = threadIdx.x & 63;
    int node = blockIdx.x * 4 + wid;
    if (node >= N) return;
    float2 bv = *(const float2*)(bias + 2 * l);
    float a0 = bv.x, a1 = bv.y;
    int idx = off[node], end = off[node + 1];
    for (; idx + 3 < end; idx += 4) {
        unsigned int e0 = edata[idx], e1 = edata[idx + 1];
        unsigned int e2 = edata[idx + 2], e3 = edata[idx + 3];
        unsigned int v0 = ((const unsigned int*)(Hb + (size_t)(e0 & 0xffff) * 128))[l];
        unsigned int v1 = ((const unsigned int*)(Hb + (size_t)(e1 & 0xffff) * 128))[l];
        unsigned int v2 = ((const unsigned int*)(Hb + (size_t)(e2 & 0xffff) * 128))[l];
        unsigned int v3 = ((const unsigned int*)(Hb + (size_t)(e3 & 0xffff) * 128))[l];
        float w0 = b2f((unsigned short)(e0 >> 16)), w1 = b2f((unsigned short)(e1 >> 16));
        float w2 = b2f((unsigned short)(e2 >> 16)), w3 = b2f((unsigned short)(e3 >> 16));
        a0 += w0 * b2f((unsigned short)v0);  a1 += w0 * b2f((unsigned short)(v0 >> 16));
        a0 += w1 * b2f((unsigned short)v1);  a1 += w1 * b2f((unsigned short)(v1 >> 16));
        a0 += w2 * b2f((unsigned short)v2);  a1 += w2 * b2f((unsigned short)(v2 >> 16));
        a0 += w3 * b2f((unsigned short)v3);  a1 += w3 * b2f((unsigned short)(v3 >> 16));
    }
    for (; idx < end; ++idx) {
        unsigned int e = edata[idx];
        unsigned int v = ((const unsigned int*)(Hb + (size_t)(e & 0xffff) * 128))[l];
        float w = b2f((unsigned short)(e >> 16));
        a0 += w * b2f((unsigned short)v);
        a1 += w * b2f((unsigned short)(v >> 16));
    }
    float s = a0 + a1;
#pragma unroll
    for (int m = 32; m >= 1; m >>= 1) s += __shfl_xor(s, m, 64);
    float mu = s * (1.f / 128.f);
    float d0 = a0 - mu, d1 = a1 - mu;
    float q = d0 * d0 + d1 * d1;
#pragma unroll
    for (int m = 32; m >= 1; m >>= 1) q += __shfl_xor(q, m, 64);
    float rs = rsqrtf(q * (1.f / 128.f) + LN_EPS);
    float2 gv = *(const float2*)(g + 2 * l);
    float2 bev = *(const float2*)(be + 2 * l);
    float r0 = fmaxf(d0 * rs * gv.x + bev.x, 0.f);
    float r1 = fmaxf(d1 * rs * gv.y + bev.y, 0.f);
    if (FINAL) {
        if (flags[0]) {
            ((float2*)outAny)[(size_t)node * 64 + l] = make_float2(r0, r1);
        } else {
            ((unsigned int*)outAny)[(size_t)node * 64 + l] = pk2(r0, r1);
        }
    } else {
        ((unsigned int*)outb)[(size_t)node * 64 + l] = pk2(r0, r1);
    }
}

extern "C" void kernel_launch(void* const* d_in, const int* in_sizes, int n_in,
                              void* d_out, int out_size, void* d_ws, size_t ws_size,
                              hipStream_t stream) {
    const unsigned short* x_u16 = (const unsigned short*)d_in[0];
    const int*            ei    = (const int*)d_in[1];

    const int N = in_sizes[0] / 128;
    const int E = in_sizes[2];
    const int B = (N + 255) >> 8;          // buckets of 256 nodes (<=256)
    const int chunk = (E + G1 - 1) / G1;

    // ---- workspace layout ----
    unsigned short* Xb = (unsigned short*)d_ws;            // N*128 bf16 (mid act)
    unsigned short* Hb = Xb + (size_t)N * 128;             // N*128 bf16
    unsigned int* gA    = (unsigned int*)(Hb + (size_t)N * 128); // E
    unsigned int* edata = gA + E;                          // E
    unsigned char* g8   = (unsigned char*)(edata + E);     // E (pad 4)
    int* cnt2d  = (int*)(g8 + ((E + 3) & ~3));             // 256*256
    int* lofs2d = cnt2d + 65536;                           // 256*256
    int* bb     = lofs2d + 65536;                          // B+1 (+pad)
    int* off    = bb + 260;                                // N+1 (+pad)
    int* flags  = off + N + 4;                             // 8
    unsigned short* Wt1 = (unsigned short*)(flags + 8);    // 16384 bf16
    unsigned short* Wt2 = Wt1 + 16384;                     // 16384 bf16
    float* sm   = (float*)(Wt2 + 16384);                   // 6*128 f32
    float* b1f  = sm;
    float* b2f_ = sm + 128;
    float* g1f  = sm + 256;
    float* g2f  = sm + 384;
    float* be1f = sm + 512;
    float* be2f = sm + 640;

    const int nodeBlocks = (N + 3) / 4;
    const int gemmBlocks = (N + 63) / 64;

    k_detect<<<1, 256, 0, stream>>>(x_u16, ei, E, flags);
    k_prep<<<64, 256, 0, stream>>>(d_in[3], d_in[5], d_in[4], d_in[6],
                                   d_in[7], d_in[9], d_in[8], d_in[10],
                                   Wt1, Wt2, sm, flags);

    // ---- CSR build: 2-pass counting sort (+2 tiny scans), coalesced writes ----
    k_p1<<<G1, 256, 0, stream>>>(ei, d_in[2], E, B, chunk, flags, gA, g8, cnt2d, lofs2d);
    k_p15a<<<1, 256, 0, stream>>>(cnt2d, bb, B);
    k_p3<<<B, 256, 0, stream>>>(gA, g8, cnt2d, lofs2d, bb, edata, off, N, B, chunk);

    // ---- layer 1 (GEMM reads d_in[0] directly, converts in staging) ----
    k_gemm<<<gemmBlocks, 256, 0, stream>>>(d_in[0], Wt1, Hb, N, flags, 1);
    k_agg_ln<false><<<nodeBlocks, 256, 0, stream>>>(Hb, edata, off, b1f, g1f, be1f, Xb, nullptr, flags, N);

    // ---- layer 2 ----
    k_gemm<<<gemmBlocks, 256, 0, stream>>>(Xb, Wt2, Hb, N, flags, 0);
    k_agg_ln<true><<<nodeBlocks, 256, 0, stream>>>(Hb, edata, off, b2f_, g2f, be2f, nullptr, d_out, flags, N);
}

// Round 7
// 138.544 us; speedup vs baseline: 3.9620x; 1.1052x over previous
//
#include <hip/hip_runtime.h>
#include <stdint.h>

#define LN_EPS 1e-5f
#define G1 256
#define P1CAP 4096
#define P3CAP 6144
#define CAPB 6144

typedef __attribute__((ext_vector_type(8))) short s16x8;
typedef __attribute__((ext_vector_type(4))) float f32x4;

__device__ __forceinline__ float b2f(unsigned short u) {
    union { unsigned int i; float f; } v; v.i = ((unsigned int)u) << 16; return v.f;
}
__device__ __forceinline__ unsigned short f2b(float f) {
    union { float f; unsigned int i; } v; v.f = f;
    unsigned int u = v.i;
    return (unsigned short)((u + 0x7fffu + ((u >> 16) & 1u)) >> 16);
}
__device__ __forceinline__ unsigned int pk2(float a, float b) {
    return (unsigned int)f2b(a) | ((unsigned int)f2b(b) << 16);
}

// flags[0] = floats are f32 (else bf16); flags[1] = edge_index is int64 (else int32)
__global__ void k_detect(const unsigned short* __restrict__ xu,
                         const int* __restrict__ ei, int E, int* __restrict__ flags) {
    __shared__ int s[2];
    int t = threadIdx.x;
    if (t < 2) s[t] = 0;
    __syncthreads();
    int c1 = 0;
    for (int i = t; i < 2048; i += 256)
        if (fabsf(b2f(xu[i])) > 1e6f) ++c1;
    if (c1) atomicAdd(&s[0], c1);
    int mn = (E < 1024) ? E : 1024;
    int z = 0;
    for (int i = t; i < mn; i += 256)
        if (ei[2 * i + 1] == 0) ++z;
    if (z) atomicAdd(&s[1], z);
    __syncthreads();
    if (t == 0) {
        flags[0] = (s[0] > 32) ? 1 : 0;
        flags[1] = (s[1] > (mn >> 1)) ? 1 : 0;
    }
}

__device__ __forceinline__ float rdf(const void* p, int i, int f32flag) {
    return f32flag ? ((const float*)p)[i] : b2f(((const unsigned short*)p)[i]);
}

// 64 blocks: W1,W2 -> transposed bf16 Wt[j][k]; block 0 also converts small params
__global__ void k_prep(const void* W1, const void* W2,
                       const void* b1, const void* b2,
                       const void* g1, const void* g2,
                       const void* be1, const void* be2,
                       unsigned short* __restrict__ Wt1, unsigned short* __restrict__ Wt2,
                       float* __restrict__ sm, const int* __restrict__ flags) {
    int t = threadIdx.x;
    int f = flags[0];
    int i = blockIdx.x * 256 + t;  // 64*256 = 16384
    int k = i >> 7, j = i & 127;
    Wt1[j * 128 + k] = f2b(rdf(W1, i, f));
    Wt2[j * 128 + k] = f2b(rdf(W2, i, f));
    if (blockIdx.x == 0 && t < 128) {
        sm[t]       = rdf(b1, t, f);
        sm[128 + t] = rdf(b2, t, f);
        sm[256 + t] = rdf(g1, t, f);
        sm[384 + t] = rdf(g2, t, f);
        sm[512 + t] = rdf(be1, t, f);
        sm[640 + t] = rdf(be2, t, f);
    }
}

// pass 1: per-block LDS binning by bucket (dst>>8); coalesced block-segment writeout
__global__ __launch_bounds__(256) void k_p1(const int* __restrict__ ei, const void* __restrict__ ew,
                                            int E, int B, int chunk,
                                            const int* __restrict__ flags,
                                            unsigned int* __restrict__ gA,
                                            unsigned char* __restrict__ g8,
                                            int* __restrict__ cnt2d, int* __restrict__ lofs2d) {
    __shared__ int hist[256], cur[256], tmp[256];
    __shared__ unsigned int bin32[P1CAP];
    __shared__ unsigned char bin8[P1CAP];
    int t = threadIdx.x, g = blockIdx.x;
    int base = g * chunk;
    int cnt = E - base; if (cnt > chunk) cnt = chunk; if (cnt < 0) cnt = 0;
    int f64 = flags[1], f32f = flags[0];
    hist[t] = 0;
    __syncthreads();
    for (int i = t; i < cnt; i += 256) {
        int e = base + i;
        int d = f64 ? ei[2 * E + 2 * e] : ei[E + e];
        atomicAdd(&hist[d >> 8], 1);
    }
    __syncthreads();
    int v = hist[t];
    tmp[t] = v;
    __syncthreads();
    for (int d = 1; d < 256; d <<= 1) {
        int x = (t >= d) ? tmp[t - d] : 0;
        __syncthreads();
        tmp[t] += x;
        __syncthreads();
    }
    int excl = tmp[t] - v;
    cur[t] = excl;
    if (t < B) { cnt2d[t * G1 + g] = v; lofs2d[t * G1 + g] = excl; }
    __syncthreads();
    for (int i = t; i < cnt; i += 256) {
        int e = base + i;
        int d, sN;
        if (f64) { d = ei[2 * E + 2 * e]; sN = ei[2 * e]; }
        else     { d = ei[E + e];         sN = ei[e]; }
        float w = f32f ? ((const float*)ew)[e] : b2f(((const unsigned short*)ew)[e]);
        int p = atomicAdd(&cur[d >> 8], 1);
        bin32[p] = (unsigned int)(sN & 0xffff) | ((unsigned int)f2b(w) << 16);
        bin8[p]  = (unsigned char)(d & 255);
    }
    __syncthreads();
    for (int j = t; j < cnt; j += 256) {
        gA[base + j] = bin32[j];
        g8[base + j] = bin8[j];
    }
}

// pass 3: gather bucket's 256 block-segments into LDS, sort by exact dst,
// write 8-aligned zero-padded segments into fixed-capacity bucket regions,
// and per-node (start,deg) into nfo.
__global__ __launch_bounds__(256) void k_p3(const unsigned int* __restrict__ gA,
                                            const unsigned char* __restrict__ g8,
                                            const int* __restrict__ cnt2d,
                                            const int* __restrict__ lofs2d,
                                            unsigned int* __restrict__ edata,
                                            uint2* __restrict__ nfo,
                                            int N, int B, int chunk) {
    __shared__ unsigned int raw[P3CAP];
    __shared__ unsigned int srt[CAPB];
    __shared__ unsigned char r8[P3CAP];
    __shared__ int h[256], tmp[256];
    __shared__ int s_cnt;
    int b = blockIdx.x, t = threadIdx.x;
    int segc = cnt2d[b * G1 + t];
    int sbase = t * chunk + lofs2d[b * G1 + t];
    // scan segment lengths -> LDS gather offsets
    int v = segc;
    tmp[t] = v;
    __syncthreads();
    for (int d = 1; d < 256; d <<= 1) {
        int x = (t >= d) ? tmp[t - d] : 0;
        __syncthreads();
        tmp[t] += x;
        __syncthreads();
    }
    int lo = tmp[t] - v;
    if (t == 255) s_cnt = tmp[255];
    for (int j = 0; j < segc; ++j) {
        int idx = lo + j;
        if (idx < P3CAP) { raw[idx] = gA[sbase + j]; r8[idx] = g8[sbase + j]; }
    }
    h[t] = 0;
    __syncthreads();
    int cnt = s_cnt; if (cnt > P3CAP) cnt = P3CAP;
    // histogram by exact dst low byte
    for (int i = t; i < cnt; i += 256) atomicAdd(&h[r8[i]], 1);
    __syncthreads();
    int deg = h[t];
    int pd = (deg + 7) & ~7;           // 8-padded segment length
    tmp[t] = pd;
    __syncthreads();
    for (int d = 1; d < 256; d <<= 1) {
        int x = (t >= d) ? tmp[t - d] : 0;
        __syncthreads();
        tmp[t] += x;
        __syncthreads();
    }
    int pexcl = tmp[t] - pd;
    int node0 = b << 8;
    int gbase = b * CAPB;
    if (node0 + t < N) nfo[node0 + t] = make_uint2((unsigned)(gbase + pexcl), (unsigned)deg);
    h[t] = pexcl;   // scatter cursor (within padded layout)
    // zero-fill srt (padding entries become src=0, w=0 -> contribute nothing)
    for (int i = t; i < CAPB; i += 256) srt[i] = 0;
    __syncthreads();
    for (int i = t; i < cnt; i += 256) {
        int p = atomicAdd(&h[r8[i]], 1);
        if (p < CAPB) srt[p] = raw[i];
    }
    __syncthreads();
    for (int i = t; i < CAPB; i += 256) edata[gbase + i] = srt[i];
}

// MFMA bf16 GEMM: H[n][j] = sum_k X[n][k]*W[k][j]; Wt bf16 [j][k] (transposed).
// layer1: X is d_in[0] (f32 or bf16 per flags[0]); else X is bf16 workspace.
__global__ __launch_bounds__(256) void k_gemm(const void* __restrict__ X,
                                              const unsigned short* __restrict__ Wt,
                                              unsigned short* __restrict__ Hb, int N,
                                              const int* __restrict__ flags, int layer1) {
    __shared__ unsigned char lds[49152];   // xs 16KB + wt 32KB
    unsigned char* xs = lds;
    unsigned char* wt = lds + 16384;
    int t = threadIdx.x;
    int node0 = blockIdx.x * 64;
    int f32in = layer1 ? flags[0] : 0;

#pragma unroll
    for (int it = 0; it < 8; ++it) {
        int c = t + it * 256;
        int row = c >> 4, cc = c & 15;
        uint4 v = *(const uint4*)(Wt + row * 128 + cc * 8);
        int off = (row * 256 + cc * 16) ^ ((row & 7) << 4);
        *(uint4*)(wt + off) = v;
    }
#pragma unroll
    for (int it = 0; it < 4; ++it) {
        int c = t + it * 256;
        int row = c >> 4, cc = c & 15;
        int g = node0 + row;
        uint4 v = make_uint4(0, 0, 0, 0);
        if (g < N) {
            if (f32in) {
                const float* xr = (const float*)X + (size_t)g * 128 + cc * 8;
                float4 f0 = *(const float4*)xr;
                float4 f1 = *(const float4*)(xr + 4);
                v.x = pk2(f0.x, f0.y); v.y = pk2(f0.z, f0.w);
                v.z = pk2(f1.x, f1.y); v.w = pk2(f1.z, f1.w);
            } else {
                v = *(const uint4*)((const unsigned short*)X + (size_t)g * 128 + cc * 8);
            }
        }
        int off = (row * 256 + cc * 16) ^ ((row & 7) << 4);
        *(uint4*)(xs + off) = v;
    }
    __syncthreads();

    int w = t >> 6, l = t & 63;
    int arow = l & 15;
    int apart = l >> 4;
    f32x4 acc[8];
#pragma unroll
    for (int ct = 0; ct < 8; ++ct) acc[ct] = (f32x4){0.f, 0.f, 0.f, 0.f};

#pragma unroll
    for (int ks = 0; ks < 4; ++ks) {
        int grow = w * 16 + arow;
        int aoff = (grow * 256 + ks * 64 + apart * 16) ^ ((grow & 7) << 4);
        s16x8 afrag = *(const s16x8*)(xs + aoff);
#pragma unroll
        for (int ct = 0; ct < 8; ++ct) {
            int brow = ct * 16 + arow;
            int boff = (brow * 256 + ks * 64 + apart * 16) ^ ((brow & 7) << 4);
            s16x8 bfrag = *(const s16x8*)(wt + boff);
            acc[ct] = __builtin_amdgcn_mfma_f32_16x16x32_bf16(afrag, bfrag, acc[ct], 0, 0, 0);
        }
    }
    int orow0 = node0 + w * 16 + apart * 4;
    int ocol = arow;
#pragma unroll
    for (int ct = 0; ct < 8; ++ct) {
#pragma unroll
        for (int r = 0; r < 4; ++r) {
            int g = orow0 + r;
            if (g < N) Hb[(size_t)g * 128 + ct * 16 + ocol] = f2b(acc[ct][r]);
        }
    }
}

// fused: out = relu(LN(bias + sum_e ew*H[src])); one wave per node.
// 8-wide batched gather: segments are 8-aligned+zero-padded, so all 8 row
// loads of a batch are issued independently (pad entries have w=0).
template <bool FINAL>
__global__ __launch_bounds__(256) void k_agg_ln(const unsigned short* __restrict__ Hb,
                                                const unsigned int* __restrict__ edata,
                                                const uint2* __restrict__ nfo,
                                                const float* __restrict__ bias,
                                                const float* __restrict__ g,
                                                const float* __restrict__ be,
                                                unsigned short* __restrict__ outb,
                                                void* __restrict__ outAny,
                                                const int* __restrict__ flags, int N) {
    int wid = threadIdx.x >> 6;
    int l = threadIdx.x & 63;
    int node = blockIdx.x * 4 + wid;
    if (node >= N) return;
    float2 bv = *(const float2*)(bias + 2 * l);
    float a0 = bv.x, a1 = bv.y;
    uint2 info = nfo[node];
    int base = (int)info.x, deg = (int)info.y;
    const unsigned int* Hl = (const unsigned int*)Hb + l;  // lane's dword column
    for (int b0 = 0; b0 < deg; b0 += 8) {
        const uint4* ep = (const uint4*)(edata + base + b0);
        uint4 q0 = ep[0];
        uint4 q1 = ep[1];
        unsigned int hv0 = Hl[(size_t)(q0.x & 0xffffu) << 6];
        unsigned int hv1 = Hl[(size_t)(q0.y & 0xffffu) << 6];
        unsigned int hv2 = Hl[(size_t)(q0.z & 0xffffu) << 6];
        unsigned int hv3 = Hl[(size_t)(q0.w & 0xffffu) << 6];
        unsigned int hv4 = Hl[(size_t)(q1.x & 0xffffu) << 6];
        unsigned int hv5 = Hl[(size_t)(q1.y & 0xffffu) << 6];
        unsigned int hv6 = Hl[(size_t)(q1.z & 0xffffu) << 6];
        unsigned int hv7 = Hl[(size_t)(q1.w & 0xffffu) << 6];
        float w0 = b2f((unsigned short)(q0.x >> 16));
        float w1 = b2f((unsigned short)(q0.y >> 16));
        float w2 = b2f((unsigned short)(q0.z >> 16));
        float w3 = b2f((unsigned short)(q0.w >> 16));
        float w4 = b2f((unsigned short)(q1.x >> 16));
        float w5 = b2f((unsigned short)(q1.y >> 16));
        float w6 = b2f((unsigned short)(q1.z >> 16));
        float w7 = b2f((unsigned short)(q1.w >> 16));
        a0 += w0 * b2f((unsigned short)hv0);  a1 += w0 * b2f((unsigned short)(hv0 >> 16));
        a0 += w1 * b2f((unsigned short)hv1);  a1 += w1 * b2f((unsigned short)(hv1 >> 16));
        a0 += w2 * b2f((unsigned short)hv2);  a1 += w2 * b2f((unsigned short)(hv2 >> 16));
        a0 += w3 * b2f((unsigned short)hv3);  a1 += w3 * b2f((unsigned short)(hv3 >> 16));
        a0 += w4 * b2f((unsigned short)hv4);  a1 += w4 * b2f((unsigned short)(hv4 >> 16));
        a0 += w5 * b2f((unsigned short)hv5);  a1 += w5 * b2f((unsigned short)(hv5 >> 16));
        a0 += w6 * b2f((unsigned short)hv6);  a1 += w6 * b2f((unsigned short)(hv6 >> 16));
        a0 += w7 * b2f((unsigned short)hv7);  a1 += w7 * b2f((unsigned short)(hv7 >> 16));
    }
    float s = a0 + a1;
#pragma unroll
    for (int m = 32; m >= 1; m >>= 1) s += __shfl_xor(s, m, 64);
    float mu = s * (1.f / 128.f);
    float d0 = a0 - mu, d1 = a1 - mu;
    float q = d0 * d0 + d1 * d1;
#pragma unroll
    for (int m = 32; m >= 1; m >>= 1) q += __shfl_xor(q, m, 64);
    float rs = rsqrtf(q * (1.f / 128.f) + LN_EPS);
    float2 gv = *(const float2*)(g + 2 * l);
    float2 bev = *(const float2*)(be + 2 * l);
    float r0 = fmaxf(d0 * rs * gv.x + bev.x, 0.f);
    float r1 = fmaxf(d1 * rs * gv.y + bev.y, 0.f);
    if (FINAL) {
        if (flags[0]) {
            ((float2*)outAny)[(size_t)node * 64 + l] = make_float2(r0, r1);
        } else {
            ((unsigned int*)outAny)[(size_t)node * 64 + l] = pk2(r0, r1);
        }
    } else {
        ((unsigned int*)outb)[(size_t)node * 64 + l] = pk2(r0, r1);
    }
}

extern "C" void kernel_launch(void* const* d_in, const int* in_sizes, int n_in,
                              void* d_out, int out_size, void* d_ws, size_t ws_size,
                              hipStream_t stream) {
    const unsigned short* x_u16 = (const unsigned short*)d_in[0];
    const int*            ei    = (const int*)d_in[1];

    const int N = in_sizes[0] / 128;
    const int E = in_sizes[2];
    const int B = (N + 255) >> 8;          // buckets of 256 nodes (<=256)
    const int chunk = (E + G1 - 1) / G1;

    // ---- workspace layout ----
    unsigned short* Xb = (unsigned short*)d_ws;            // N*128 bf16 (mid act)
    unsigned short* Hb = Xb + (size_t)N * 128;             // N*128 bf16
    unsigned int* gA    = (unsigned int*)(Hb + (size_t)N * 128); // E
    unsigned int* edata = gA + E;                          // B*CAPB
    unsigned char* g8   = (unsigned char*)(edata + (size_t)B * CAPB); // E (pad 4)
    int* cnt2d  = (int*)(g8 + ((E + 3) & ~3));             // 256*256
    int* lofs2d = cnt2d + 65536;                           // 256*256
    uint2* nfo  = (uint2*)(lofs2d + 65536);                // N
    int* flags  = (int*)(nfo + N);                         // 8
    unsigned short* Wt1 = (unsigned short*)(flags + 8);    // 16384 bf16
    unsigned short* Wt2 = Wt1 + 16384;                     // 16384 bf16
    float* sm   = (float*)(Wt2 + 16384);                   // 6*128 f32
    float* b1f  = sm;
    float* b2f_ = sm + 128;
    float* g1f  = sm + 256;
    float* g2f  = sm + 384;
    float* be1f = sm + 512;
    float* be2f = sm + 640;

    const int nodeBlocks = (N + 3) / 4;
    const int gemmBlocks = (N + 63) / 64;

    k_detect<<<1, 256, 0, stream>>>(x_u16, ei, E, flags);
    k_prep<<<64, 256, 0, stream>>>(d_in[3], d_in[5], d_in[4], d_in[6],
                                   d_in[7], d_in[9], d_in[8], d_in[10],
                                   Wt1, Wt2, sm, flags);

    // ---- CSR build: 2-pass counting sort with padded bucket regions ----
    k_p1<<<G1, 256, 0, stream>>>(ei, d_in[2], E, B, chunk, flags, gA, g8, cnt2d, lofs2d);
    k_p3<<<B, 256, 0, stream>>>(gA, g8, cnt2d, lofs2d, edata, nfo, N, B, chunk);

    // ---- layer 1 (GEMM reads d_in[0] directly, converts in staging) ----
    k_gemm<<<gemmBlocks, 256, 0, stream>>>(d_in[0], Wt1, Hb, N, flags, 1);
    k_agg_ln<false><<<nodeBlocks, 256, 0, stream>>>(Hb, edata, nfo, b1f, g1f, be1f, Xb, nullptr, flags, N);

    // ---- layer 2 ----
    k_gemm<<<gemmBlocks, 256, 0, stream>>>(Xb, Wt2, Hb, N, flags, 0);
    k_agg_ln<true><<<nodeBlocks, 256, 0, stream>>>(Hb, edata, nfo, b2f_, g2f, be2f, nullptr, d_out, flags, N);
}

// Round 8
// 125.464 us; speedup vs baseline: 4.3751x; 1.1043x over previous
//
#include <hip/hip_runtime.h>
#include <hip/hip_fp16.h>
#include <stdint.h>

#define LN_EPS 1e-5f
#define G1 256
#define P1CAP 4096
#define P3CAP 6144
#define CAPB 6144

typedef __attribute__((ext_vector_type(8))) short s16x8;
typedef __attribute__((ext_vector_type(4))) float f32x4;

__device__ __forceinline__ float b2f(unsigned short u) {
    union { unsigned int i; float f; } v; v.i = ((unsigned int)u) << 16; return v.f;
}
__device__ __forceinline__ unsigned short f2b(float f) {
    union { float f; unsigned int i; } v; v.f = f;
    unsigned int u = v.i;
    return (unsigned short)((u + 0x7fffu + ((u >> 16) & 1u)) >> 16);
}
__device__ __forceinline__ unsigned int pk2(float a, float b) {
    return (unsigned int)f2b(a) | ((unsigned int)f2b(b) << 16);
}
__device__ __forceinline__ __half2 u2h2(unsigned int u) {
    union { unsigned int i; __half2 h; } v; v.i = u; return v.h;
}

// flags[0] = floats are f32 (else bf16); flags[1] = edge_index is int64 (else int32)
__global__ void k_detect(const unsigned short* __restrict__ xu,
                         const int* __restrict__ ei, int E, int* __restrict__ flags) {
    __shared__ int s[2];
    int t = threadIdx.x;
    if (t < 2) s[t] = 0;
    __syncthreads();
    int c1 = 0;
    for (int i = t; i < 2048; i += 256)
        if (fabsf(b2f(xu[i])) > 1e6f) ++c1;
    if (c1) atomicAdd(&s[0], c1);
    int mn = (E < 1024) ? E : 1024;
    int z = 0;
    for (int i = t; i < mn; i += 256)
        if (ei[2 * i + 1] == 0) ++z;
    if (z) atomicAdd(&s[1], z);
    __syncthreads();
    if (t == 0) {
        flags[0] = (s[0] > 32) ? 1 : 0;
        flags[1] = (s[1] > (mn >> 1)) ? 1 : 0;
    }
}

__device__ __forceinline__ float rdf(const void* p, int i, int f32flag) {
    return f32flag ? ((const float*)p)[i] : b2f(((const unsigned short*)p)[i]);
}

// 64 blocks: W1,W2 -> transposed bf16 Wt[j][k]; block 0 also converts small params
__global__ void k_prep(const void* W1, const void* W2,
                       const void* b1, const void* b2,
                       const void* g1, const void* g2,
                       const void* be1, const void* be2,
                       unsigned short* __restrict__ Wt1, unsigned short* __restrict__ Wt2,
                       float* __restrict__ sm, const int* __restrict__ flags) {
    int t = threadIdx.x;
    int f = flags[0];
    int i = blockIdx.x * 256 + t;  // 64*256 = 16384
    int k = i >> 7, j = i & 127;
    Wt1[j * 128 + k] = f2b(rdf(W1, i, f));
    Wt2[j * 128 + k] = f2b(rdf(W2, i, f));
    if (blockIdx.x == 0 && t < 128) {
        sm[t]       = rdf(b1, t, f);
        sm[128 + t] = rdf(b2, t, f);
        sm[256 + t] = rdf(g1, t, f);
        sm[384 + t] = rdf(g2, t, f);
        sm[512 + t] = rdf(be1, t, f);
        sm[640 + t] = rdf(be2, t, f);
    }
}

// pass 1: per-block LDS binning by bucket (dst>>8); weight packed as f16
__global__ __launch_bounds__(256) void k_p1(const int* __restrict__ ei, const void* __restrict__ ew,
                                            int E, int B, int chunk,
                                            const int* __restrict__ flags,
                                            unsigned int* __restrict__ gA,
                                            unsigned char* __restrict__ g8,
                                            int* __restrict__ cnt2d, int* __restrict__ lofs2d) {
    __shared__ int hist[256], cur[256], tmp[256];
    __shared__ unsigned int bin32[P1CAP];
    __shared__ unsigned char bin8[P1CAP];
    int t = threadIdx.x, g = blockIdx.x;
    int base = g * chunk;
    int cnt = E - base; if (cnt > chunk) cnt = chunk; if (cnt < 0) cnt = 0;
    int f64 = flags[1], f32f = flags[0];
    hist[t] = 0;
    __syncthreads();
    for (int i = t; i < cnt; i += 256) {
        int e = base + i;
        int d = f64 ? ei[2 * E + 2 * e] : ei[E + e];
        atomicAdd(&hist[d >> 8], 1);
    }
    __syncthreads();
    int v = hist[t];
    tmp[t] = v;
    __syncthreads();
    for (int d = 1; d < 256; d <<= 1) {
        int x = (t >= d) ? tmp[t - d] : 0;
        __syncthreads();
        tmp[t] += x;
        __syncthreads();
    }
    int excl = tmp[t] - v;
    cur[t] = excl;
    if (t < B) { cnt2d[t * G1 + g] = v; lofs2d[t * G1 + g] = excl; }
    __syncthreads();
    for (int i = t; i < cnt; i += 256) {
        int e = base + i;
        int d, sN;
        if (f64) { d = ei[2 * E + 2 * e]; sN = ei[2 * e]; }
        else     { d = ei[E + e];         sN = ei[e]; }
        float w = f32f ? ((const float*)ew)[e] : b2f(((const unsigned short*)ew)[e]);
        __half wh = __float2half(w);
        int p = atomicAdd(&cur[d >> 8], 1);
        bin32[p] = (unsigned int)(sN & 0xffff) | ((unsigned int)__half_as_ushort(wh) << 16);
        bin8[p]  = (unsigned char)(d & 255);
    }
    __syncthreads();
    for (int j = t; j < cnt; j += 256) {
        gA[base + j] = bin32[j];
        g8[base + j] = bin8[j];
    }
}

// pass 3: gather bucket's 256 block-segments into LDS, sort by exact dst,
// write 8-aligned zero-padded segments into fixed-capacity bucket regions.
__global__ __launch_bounds__(256) void k_p3(const unsigned int* __restrict__ gA,
                                            const unsigned char* __restrict__ g8,
                                            const int* __restrict__ cnt2d,
                                            const int* __restrict__ lofs2d,
                                            unsigned int* __restrict__ edata,
                                            uint2* __restrict__ nfo,
                                            int N, int B, int chunk) {
    __shared__ unsigned int raw[P3CAP];
    __shared__ unsigned int srt[CAPB];
    __shared__ unsigned char r8[P3CAP];
    __shared__ int h[256], tmp[256];
    __shared__ int s_cnt;
    int b = blockIdx.x, t = threadIdx.x;
    int segc = cnt2d[b * G1 + t];
    int sbase = t * chunk + lofs2d[b * G1 + t];
    // scan segment lengths -> LDS gather offsets
    int v = segc;
    tmp[t] = v;
    __syncthreads();
    for (int d = 1; d < 256; d <<= 1) {
        int x = (t >= d) ? tmp[t - d] : 0;
        __syncthreads();
        tmp[t] += x;
        __syncthreads();
    }
    int lo = tmp[t] - v;
    if (t == 255) s_cnt = tmp[255];
    // gather my segment into LDS, 4 independent loads in flight
    int j = 0;
    for (; j + 3 < segc; j += 4) {
        unsigned int a0 = gA[sbase + j], a1 = gA[sbase + j + 1];
        unsigned int a2 = gA[sbase + j + 2], a3 = gA[sbase + j + 3];
        unsigned char c0 = g8[sbase + j], c1 = g8[sbase + j + 1];
        unsigned char c2 = g8[sbase + j + 2], c3 = g8[sbase + j + 3];
        int i0 = lo + j;
        if (i0 + 3 < P3CAP) {
            raw[i0] = a0; raw[i0 + 1] = a1; raw[i0 + 2] = a2; raw[i0 + 3] = a3;
            r8[i0] = c0; r8[i0 + 1] = c1; r8[i0 + 2] = c2; r8[i0 + 3] = c3;
        }
    }
    for (; j < segc; ++j) {
        int idx = lo + j;
        if (idx < P3CAP) { raw[idx] = gA[sbase + j]; r8[idx] = g8[sbase + j]; }
    }
    h[t] = 0;
    __syncthreads();
    int cnt = s_cnt; if (cnt > P3CAP) cnt = P3CAP;
    for (int i = t; i < cnt; i += 256) atomicAdd(&h[r8[i]], 1);
    __syncthreads();
    int deg = h[t];
    int pd = (deg + 7) & ~7;
    tmp[t] = pd;
    __syncthreads();
    for (int d = 1; d < 256; d <<= 1) {
        int x = (t >= d) ? tmp[t - d] : 0;
        __syncthreads();
        tmp[t] += x;
        __syncthreads();
    }
    int pexcl = tmp[t] - pd;
    int node0 = b << 8;
    int gbase = b * CAPB;
    if (node0 + t < N) nfo[node0 + t] = make_uint2((unsigned)(gbase + pexcl), (unsigned)deg);
    h[t] = pexcl;
    for (int i = t; i < CAPB; i += 256) srt[i] = 0;
    __syncthreads();
    for (int i = t; i < cnt; i += 256) {
        int p = atomicAdd(&h[r8[i]], 1);
        if (p < CAPB) srt[p] = raw[i];
    }
    __syncthreads();
    for (int i = t; i < CAPB; i += 256) edata[gbase + i] = srt[i];
}

// MFMA bf16 GEMM: H[n][j] = sum_k X[n][k]*W[k][j]; output stored as f16.
__global__ __launch_bounds__(256) void k_gemm(const void* __restrict__ X,
                                              const unsigned short* __restrict__ Wt,
                                              unsigned short* __restrict__ Hh, int N,
                                              const int* __restrict__ flags, int layer1) {
    __shared__ unsigned char lds[49152];   // xs 16KB + wt 32KB
    unsigned char* xs = lds;
    unsigned char* wt = lds + 16384;
    int t = threadIdx.x;
    int node0 = blockIdx.x * 64;
    int f32in = layer1 ? flags[0] : 0;

#pragma unroll
    for (int it = 0; it < 8; ++it) {
        int c = t + it * 256;
        int row = c >> 4, cc = c & 15;
        uint4 v = *(const uint4*)(Wt + row * 128 + cc * 8);
        int off = (row * 256 + cc * 16) ^ ((row & 7) << 4);
        *(uint4*)(wt + off) = v;
    }
#pragma unroll
    for (int it = 0; it < 4; ++it) {
        int c = t + it * 256;
        int row = c >> 4, cc = c & 15;
        int g = node0 + row;
        uint4 v = make_uint4(0, 0, 0, 0);
        if (g < N) {
            if (f32in) {
                const float* xr = (const float*)X + (size_t)g * 128 + cc * 8;
                float4 f0 = *(const float4*)xr;
                float4 f1 = *(const float4*)(xr + 4);
                v.x = pk2(f0.x, f0.y); v.y = pk2(f0.z, f0.w);
                v.z = pk2(f1.x, f1.y); v.w = pk2(f1.z, f1.w);
            } else {
                v = *(const uint4*)((const unsigned short*)X + (size_t)g * 128 + cc * 8);
            }
        }
        int off = (row * 256 + cc * 16) ^ ((row & 7) << 4);
        *(uint4*)(xs + off) = v;
    }
    __syncthreads();

    int w = t >> 6, l = t & 63;
    int arow = l & 15;
    int apart = l >> 4;
    f32x4 acc[8];
#pragma unroll
    for (int ct = 0; ct < 8; ++ct) acc[ct] = (f32x4){0.f, 0.f, 0.f, 0.f};

#pragma unroll
    for (int ks = 0; ks < 4; ++ks) {
        int grow = w * 16 + arow;
        int aoff = (grow * 256 + ks * 64 + apart * 16) ^ ((grow & 7) << 4);
        s16x8 afrag = *(const s16x8*)(xs + aoff);
#pragma unroll
        for (int ct = 0; ct < 8; ++ct) {
            int brow = ct * 16 + arow;
            int boff = (brow * 256 + ks * 64 + apart * 16) ^ ((brow & 7) << 4);
            s16x8 bfrag = *(const s16x8*)(wt + boff);
            acc[ct] = __builtin_amdgcn_mfma_f32_16x16x32_bf16(afrag, bfrag, acc[ct], 0, 0, 0);
        }
    }
    int orow0 = node0 + w * 16 + apart * 4;
    int ocol = arow;
#pragma unroll
    for (int ct = 0; ct < 8; ++ct) {
#pragma unroll
        for (int r = 0; r < 4; ++r) {
            int g = orow0 + r;
            if (g < N) {
                __half hh = __float2half(acc[ct][r]);
                Hh[(size_t)g * 128 + ct * 16 + ocol] = __half_as_ushort(hh);
            }
        }
    }
}

// fused: out = relu(LN(bias + sum_e ew*H[src])); 2 nodes per wave (32 lanes each).
// lane owns features 4*l32 .. 4*l32+3; packed f16 accumulation via v_pk_fma_f16.
template <bool FINAL>
__global__ __launch_bounds__(256) void k_agg_ln(const unsigned short* __restrict__ Hh,
                                                const unsigned int* __restrict__ edata,
                                                const uint2* __restrict__ nfo,
                                                const float* __restrict__ bias,
                                                const float* __restrict__ g,
                                                const float* __restrict__ be,
                                                unsigned short* __restrict__ outb,
                                                void* __restrict__ outAny,
                                                const int* __restrict__ flags, int N) {
    int t = threadIdx.x;
    int l32 = t & 31;
    int node = blockIdx.x * 8 + (t >> 5);
    if (node >= N) return;
    uint2 info = nfo[node];
    int base = (int)info.x, deg = (int)info.y;
    __half2 acc01 = u2h2(0u), acc23 = u2h2(0u);
    const uint2* Hl = (const uint2*)Hh + l32;   // + (row << 5)
    for (int b0 = 0; b0 < deg; b0 += 8) {
        const uint4* ep = (const uint4*)(edata + base + b0);
        uint4 q0 = ep[0], q1 = ep[1];
        uint2 h0 = Hl[(size_t)(q0.x & 0xffffu) << 5];
        uint2 h1 = Hl[(size_t)(q0.y & 0xffffu) << 5];
        uint2 h2 = Hl[(size_t)(q0.z & 0xffffu) << 5];
        uint2 h3 = Hl[(size_t)(q0.w & 0xffffu) << 5];
        uint2 h4 = Hl[(size_t)(q1.x & 0xffffu) << 5];
        uint2 h5 = Hl[(size_t)(q1.y & 0xffffu) << 5];
        uint2 h6 = Hl[(size_t)(q1.z & 0xffffu) << 5];
        uint2 h7 = Hl[(size_t)(q1.w & 0xffffu) << 5];
        unsigned int wb;
        __half2 w2;
        wb = q0.x >> 16; w2 = u2h2(wb | (wb << 16));
        acc01 = __hfma2(u2h2(h0.x), w2, acc01);  acc23 = __hfma2(u2h2(h0.y), w2, acc23);
        wb = q0.y >> 16; w2 = u2h2(wb | (wb << 16));
        acc01 = __hfma2(u2h2(h1.x), w2, acc01);  acc23 = __hfma2(u2h2(h1.y), w2, acc23);
        wb = q0.z >> 16; w2 = u2h2(wb | (wb << 16));
        acc01 = __hfma2(u2h2(h2.x), w2, acc01);  acc23 = __hfma2(u2h2(h2.y), w2, acc23);
        wb = q0.w >> 16; w2 = u2h2(wb | (wb << 16));
        acc01 = __hfma2(u2h2(h3.x), w2, acc01);  acc23 = __hfma2(u2h2(h3.y), w2, acc23);
        wb = q1.x >> 16; w2 = u2h2(wb | (wb << 16));
        acc01 = __hfma2(u2h2(h4.x), w2, acc01);  acc23 = __hfma2(u2h2(h4.y), w2, acc23);
        wb = q1.y >> 16; w2 = u2h2(wb | (wb << 16));
        acc01 = __hfma2(u2h2(h5.x), w2, acc01);  acc23 = __hfma2(u2h2(h5.y), w2, acc23);
        wb = q1.z >> 16; w2 = u2h2(wb | (wb << 16));
        acc01 = __hfma2(u2h2(h6.x), w2, acc01);  acc23 = __hfma2(u2h2(h6.y), w2, acc23);
        wb = q1.w >> 16; w2 = u2h2(wb | (wb << 16));
        acc01 = __hfma2(u2h2(h7.x), w2, acc01);  acc23 = __hfma2(u2h2(h7.y), w2, acc23);
    }
    float4 bv = ((const float4*)bias)[l32];
    float a0 = __low2float(acc01) + bv.x;
    float a1 = __high2float(acc01) + bv.y;
    float a2 = __low2float(acc23) + bv.z;
    float a3 = __high2float(acc23) + bv.w;
    // LayerNorm over 128 features spread 4-per-lane across 32 lanes
    float s = (a0 + a1) + (a2 + a3);
#pragma unroll
    for (int m = 16; m >= 1; m >>= 1) s += __shfl_xor(s, m, 64);
    float mu = s * (1.f / 128.f);
    float d0 = a0 - mu, d1 = a1 - mu, d2 = a2 - mu, d3 = a3 - mu;
    float q = (d0 * d0 + d1 * d1) + (d2 * d2 + d3 * d3);
#pragma unroll
    for (int m = 16; m >= 1; m >>= 1) q += __shfl_xor(q, m, 64);
    float rs = rsqrtf(q * (1.f / 128.f) + LN_EPS);
    float4 gv = ((const float4*)g)[l32];
    float4 bev = ((const float4*)be)[l32];
    float r0 = fmaxf(d0 * rs * gv.x + bev.x, 0.f);
    float r1 = fmaxf(d1 * rs * gv.y + bev.y, 0.f);
    float r2 = fmaxf(d2 * rs * gv.z + bev.z, 0.f);
    float r3 = fmaxf(d3 * rs * gv.w + bev.w, 0.f);
    if (FINAL) {
        if (flags[0]) {
            ((float4*)outAny)[(size_t)node * 32 + l32] = make_float4(r0, r1, r2, r3);
        } else {
            uint2 o; o.x = pk2(r0, r1); o.y = pk2(r2, r3);
            ((uint2*)outAny)[(size_t)node * 32 + l32] = o;
        }
    } else {
        uint2 o; o.x = pk2(r0, r1); o.y = pk2(r2, r3);
        ((uint2*)outb)[(size_t)node * 32 + l32] = o;
    }
}

extern "C" void kernel_launch(void* const* d_in, const int* in_sizes, int n_in,
                              void* d_out, int out_size, void* d_ws, size_t ws_size,
                              hipStream_t stream) {
    const unsigned short* x_u16 = (const unsigned short*)d_in[0];
    const int*            ei    = (const int*)d_in[1];

    const int N = in_sizes[0] / 128;
    const int E = in_sizes[2];
    const int B = (N + 255) >> 8;          // buckets of 256 nodes (<=256)
    const int chunk = (E + G1 - 1) / G1;

    // ---- workspace layout ----
    unsigned short* Xb = (unsigned short*)d_ws;            // N*128 bf16 (mid act)
    unsigned short* Hh = Xb + (size_t)N * 128;             // N*128 f16
    unsigned int* gA    = (unsigned int*)(Hh + (size_t)N * 128); // E
    unsigned int* edata = gA + E;                          // B*CAPB
    unsigned char* g8   = (unsigned char*)(edata + (size_t)B * CAPB); // E (pad 4)
    int* cnt2d  = (int*)(g8 + ((E + 3) & ~3));             // 256*256
    int* lofs2d = cnt2d + 65536;                           // 256*256
    uint2* nfo  = (uint2*)(lofs2d + 65536);                // N
    int* flags  = (int*)(nfo + N);                         // 8
    unsigned short* Wt1 = (unsigned short*)(flags + 8);    // 16384 bf16
    unsigned short* Wt2 = Wt1 + 16384;                     // 16384 bf16
    float* sm   = (float*)(Wt2 + 16384);                   // 6*128 f32
    float* b1f  = sm;
    float* b2f_ = sm + 128;
    float* g1f  = sm + 256;
    float* g2f  = sm + 384;
    float* be1f = sm + 512;
    float* be2f = sm + 640;

    const int nodeBlocks = (N + 7) / 8;
    const int gemmBlocks = (N + 63) / 64;

    k_detect<<<1, 256, 0, stream>>>(x_u16, ei, E, flags);
    k_prep<<<64, 256, 0, stream>>>(d_in[3], d_in[5], d_in[4], d_in[6],
                                   d_in[7], d_in[9], d_in[8], d_in[10],
                                   Wt1, Wt2, sm, flags);

    // ---- CSR build: 2-pass counting sort with padded bucket regions ----
    k_p1<<<G1, 256, 0, stream>>>(ei, d_in[2], E, B, chunk, flags, gA, g8, cnt2d, lofs2d);
    k_p3<<<B, 256, 0, stream>>>(gA, g8, cnt2d, lofs2d, edata, nfo, N, B, chunk);

    // ---- layer 1 (GEMM reads d_in[0] directly, converts in staging) ----
    k_gemm<<<gemmBlocks, 256, 0, stream>>>(d_in[0], Wt1, Hh, N, flags, 1);
    k_agg_ln<false><<<nodeBlocks, 256, 0, stream>>>(Hh, edata, nfo, b1f, g1f, be1f, Xb, nullptr, flags, N);

    // ---- layer 2 ----
    k_gemm<<<gemmBlocks, 256, 0, stream>>>(Xb, Wt2, Hh, N, flags, 0);
    k_agg_ln<true><<<nodeBlocks, 256, 0, stream>>>(Hh, edata, nfo, b2f_, g2f, be2f, nullptr, d_out, flags, N);
}

// Round 9
// 121.661 us; speedup vs baseline: 4.5118x; 1.0313x over previous
//
#include <hip/hip_runtime.h>
#include <hip/hip_fp16.h>
#include <stdint.h>

#define LN_EPS 1e-5f
#define G1 256
#define P1CAP 4096
#define P3CAP 6144
#define CAPB 6144

typedef __attribute__((ext_vector_type(8))) short s16x8;
typedef __attribute__((ext_vector_type(4))) float f32x4;

__device__ __forceinline__ float b2f(unsigned short u) {
    union { unsigned int i; float f; } v; v.i = ((unsigned int)u) << 16; return v.f;
}
__device__ __forceinline__ unsigned short f2b(float f) {
    union { float f; unsigned int i; } v; v.f = f;
    unsigned int u = v.i;
    return (unsigned short)((u + 0x7fffu + ((u >> 16) & 1u)) >> 16);
}
__device__ __forceinline__ unsigned int pk2(float a, float b) {
    return (unsigned int)f2b(a) | ((unsigned int)f2b(b) << 16);
}
__device__ __forceinline__ __half2 u2h2(unsigned int u) {
    union { unsigned int i; __half2 h; } v; v.i = u; return v.h;
}

__device__ __forceinline__ float rdf(const void* p, int i, int f32flag) {
    return f32flag ? ((const float*)p)[i] : b2f(((const unsigned short*)p)[i]);
}

// 64 blocks: W1,W2 -> transposed bf16 Wt[j][k]; block 0 also converts small params
__global__ void k_prep(const void* W1, const void* W2,
                       const void* b1, const void* b2,
                       const void* g1, const void* g2,
                       const void* be1, const void* be2,
                       unsigned short* __restrict__ Wt1, unsigned short* __restrict__ Wt2,
                       float* __restrict__ sm, const int* __restrict__ flags) {
    int t = threadIdx.x;
    int f = flags[0];
    int i = blockIdx.x * 256 + t;  // 64*256 = 16384
    int k = i >> 7, j = i & 127;
    Wt1[j * 128 + k] = f2b(rdf(W1, i, f));
    Wt2[j * 128 + k] = f2b(rdf(W2, i, f));
    if (blockIdx.x == 0 && t < 128) {
        sm[t]       = rdf(b1, t, f);
        sm[128 + t] = rdf(b2, t, f);
        sm[256 + t] = rdf(g1, t, f);
        sm[384 + t] = rdf(g2, t, f);
        sm[512 + t] = rdf(be1, t, f);
        sm[640 + t] = rdf(be2, t, f);
    }
}

// pass 1: inline dtype-detect (block-local; block 0 publishes flags), then
// per-block LDS binning by bucket (dst>>8); weight packed as f16.
__global__ __launch_bounds__(256) void k_p1(const unsigned short* __restrict__ xu,
                                            const int* __restrict__ ei, const void* __restrict__ ew,
                                            int E, int B, int chunk,
                                            unsigned int* __restrict__ gA,
                                            unsigned char* __restrict__ g8,
                                            int* __restrict__ cnt2d, int* __restrict__ lofs2d,
                                            int* __restrict__ flags) {
    __shared__ int hist[256], cur[256], tmp[256];
    __shared__ unsigned int bin32[P1CAP];
    __shared__ unsigned char bin8[P1CAP];
    int t = threadIdx.x, g = blockIdx.x;
    // ---- local dtype detection ----
    if (t < 2) hist[t] = 0;
    __syncthreads();
    int c1 = 0;
    for (int i = t; i < 2048; i += 256)
        if (fabsf(b2f(xu[i])) > 1e6f) ++c1;
    if (c1) atomicAdd(&hist[0], c1);
    int mn = (E < 1024) ? E : 1024;
    int z = 0;
    for (int i = t; i < mn; i += 256)
        if (ei[2 * i + 1] == 0) ++z;
    if (z) atomicAdd(&hist[1], z);
    __syncthreads();
    int f32f = (hist[0] > 32) ? 1 : 0;
    int f64  = (hist[1] > (mn >> 1)) ? 1 : 0;
    if (g == 0 && t == 0) { flags[0] = f32f; flags[1] = f64; }
    __syncthreads();
    // ---- binning ----
    int base = g * chunk;
    int cnt = E - base; if (cnt > chunk) cnt = chunk; if (cnt < 0) cnt = 0;
    hist[t] = 0;
    __syncthreads();
    for (int i = t; i < cnt; i += 256) {
        int e = base + i;
        int d = f64 ? ei[2 * E + 2 * e] : ei[E + e];
        atomicAdd(&hist[d >> 8], 1);
    }
    __syncthreads();
    int v = hist[t];
    tmp[t] = v;
    __syncthreads();
    for (int d = 1; d < 256; d <<= 1) {
        int x = (t >= d) ? tmp[t - d] : 0;
        __syncthreads();
        tmp[t] += x;
        __syncthreads();
    }
    int excl = tmp[t] - v;
    cur[t] = excl;
    if (t < B) { cnt2d[t * G1 + g] = v; lofs2d[t * G1 + g] = excl; }
    __syncthreads();
    for (int i = t; i < cnt; i += 256) {
        int e = base + i;
        int d, sN;
        if (f64) { d = ei[2 * E + 2 * e]; sN = ei[2 * e]; }
        else     { d = ei[E + e];         sN = ei[e]; }
        float w = f32f ? ((const float*)ew)[e] : b2f(((const unsigned short*)ew)[e]);
        __half wh = __float2half(w);
        int p = atomicAdd(&cur[d >> 8], 1);
        bin32[p] = (unsigned int)(sN & 0xffff) | ((unsigned int)__half_as_ushort(wh) << 16);
        bin8[p]  = (unsigned char)(d & 255);
    }
    __syncthreads();
    for (int j = t; j < cnt; j += 256) {
        gA[base + j] = bin32[j];
        g8[base + j] = bin8[j];
    }
}

// pass 3: gather bucket's 256 block-segments into LDS, sort by exact dst,
// write 8-aligned zero-padded segments; only the used padded region is written.
__global__ __launch_bounds__(256) void k_p3(const unsigned int* __restrict__ gA,
                                            const unsigned char* __restrict__ g8,
                                            const int* __restrict__ cnt2d,
                                            const int* __restrict__ lofs2d,
                                            unsigned int* __restrict__ edata,
                                            uint2* __restrict__ nfo,
                                            int N, int B, int chunk) {
    __shared__ unsigned int raw[P3CAP];
    __shared__ unsigned int srt[CAPB];
    __shared__ unsigned char r8[P3CAP];
    __shared__ int h[256], tmp[256];
    __shared__ int s_cnt;
    int b = blockIdx.x, t = threadIdx.x;
    int segc = cnt2d[b * G1 + t];
    int sbase = t * chunk + lofs2d[b * G1 + t];
    // scan segment lengths -> LDS gather offsets
    int v = segc;
    tmp[t] = v;
    __syncthreads();
    for (int d = 1; d < 256; d <<= 1) {
        int x = (t >= d) ? tmp[t - d] : 0;
        __syncthreads();
        tmp[t] += x;
        __syncthreads();
    }
    int lo = tmp[t] - v;
    if (t == 255) s_cnt = tmp[255];
    // gather my segment into LDS, 4 independent loads in flight
    int j = 0;
    for (; j + 3 < segc; j += 4) {
        unsigned int a0 = gA[sbase + j], a1 = gA[sbase + j + 1];
        unsigned int a2 = gA[sbase + j + 2], a3 = gA[sbase + j + 3];
        unsigned char c0 = g8[sbase + j], c1 = g8[sbase + j + 1];
        unsigned char c2 = g8[sbase + j + 2], c3 = g8[sbase + j + 3];
        int i0 = lo + j;
        if (i0 + 3 < P3CAP) {
            raw[i0] = a0; raw[i0 + 1] = a1; raw[i0 + 2] = a2; raw[i0 + 3] = a3;
            r8[i0] = c0; r8[i0 + 1] = c1; r8[i0 + 2] = c2; r8[i0 + 3] = c3;
        }
    }
    for (; j < segc; ++j) {
        int idx = lo + j;
        if (idx < P3CAP) { raw[idx] = gA[sbase + j]; r8[idx] = g8[sbase + j]; }
    }
    h[t] = 0;
    __syncthreads();
    int cnt = s_cnt; if (cnt > P3CAP) cnt = P3CAP;
    for (int i = t; i < cnt; i += 256) atomicAdd(&h[r8[i]], 1);
    __syncthreads();
    int deg = h[t];
    int pd = (deg + 7) & ~7;
    tmp[t] = pd;
    __syncthreads();
    for (int d = 1; d < 256; d <<= 1) {
        int x = (t >= d) ? tmp[t - d] : 0;
        __syncthreads();
        tmp[t] += x;
        __syncthreads();
    }
    int pexcl = tmp[t] - pd;
    int padTot = tmp[255]; if (padTot > CAPB) padTot = CAPB;
    int node0 = b << 8;
    int gbase = b * CAPB;
    if (node0 + t < N) nfo[node0 + t] = make_uint2((unsigned)(gbase + pexcl), (unsigned)deg);
    h[t] = pexcl;
    for (int i = t; i < padTot; i += 256) srt[i] = 0;
    __syncthreads();
    for (int i = t; i < cnt; i += 256) {
        int p = atomicAdd(&h[r8[i]], 1);
        if (p < CAPB) srt[p] = raw[i];
    }
    __syncthreads();
    for (int i = t; i < padTot; i += 256) edata[gbase + i] = srt[i];
}

// MFMA bf16 GEMM: H[n][j] = sum_k X[n][k]*W[k][j]; output stored as f16.
__global__ __launch_bounds__(256) void k_gemm(const void* __restrict__ X,
                                              const unsigned short* __restrict__ Wt,
                                              unsigned short* __restrict__ Hh, int N,
                                              const int* __restrict__ flags, int layer1) {
    __shared__ unsigned char lds[49152];   // xs 16KB + wt 32KB
    unsigned char* xs = lds;
    unsigned char* wt = lds + 16384;
    int t = threadIdx.x;
    int node0 = blockIdx.x * 64;
    int f32in = layer1 ? flags[0] : 0;

#pragma unroll
    for (int it = 0; it < 8; ++it) {
        int c = t + it * 256;
        int row = c >> 4, cc = c & 15;
        uint4 v = *(const uint4*)(Wt + row * 128 + cc * 8);
        int off = (row * 256 + cc * 16) ^ ((row & 7) << 4);
        *(uint4*)(wt + off) = v;
    }
#pragma unroll
    for (int it = 0; it < 4; ++it) {
        int c = t + it * 256;
        int row = c >> 4, cc = c & 15;
        int g = node0 + row;
        uint4 v = make_uint4(0, 0, 0, 0);
        if (g < N) {
            if (f32in) {
                const float* xr = (const float*)X + (size_t)g * 128 + cc * 8;
                float4 f0 = *(const float4*)xr;
                float4 f1 = *(const float4*)(xr + 4);
                v.x = pk2(f0.x, f0.y); v.y = pk2(f0.z, f0.w);
                v.z = pk2(f1.x, f1.y); v.w = pk2(f1.z, f1.w);
            } else {
                v = *(const uint4*)((const unsigned short*)X + (size_t)g * 128 + cc * 8);
            }
        }
        int off = (row * 256 + cc * 16) ^ ((row & 7) << 4);
        *(uint4*)(xs + off) = v;
    }
    __syncthreads();

    int w = t >> 6, l = t & 63;
    int arow = l & 15;
    int apart = l >> 4;
    f32x4 acc[8];
#pragma unroll
    for (int ct = 0; ct < 8; ++ct) acc[ct] = (f32x4){0.f, 0.f, 0.f, 0.f};

#pragma unroll
    for (int ks = 0; ks < 4; ++ks) {
        int grow = w * 16 + arow;
        int aoff = (grow * 256 + ks * 64 + apart * 16) ^ ((grow & 7) << 4);
        s16x8 afrag = *(const s16x8*)(xs + aoff);
#pragma unroll
        for (int ct = 0; ct < 8; ++ct) {
            int brow = ct * 16 + arow;
            int boff = (brow * 256 + ks * 64 + apart * 16) ^ ((brow & 7) << 4);
            s16x8 bfrag = *(const s16x8*)(wt + boff);
            acc[ct] = __builtin_amdgcn_mfma_f32_16x16x32_bf16(afrag, bfrag, acc[ct], 0, 0, 0);
        }
    }
    int orow0 = node0 + w * 16 + apart * 4;
    int ocol = arow;
#pragma unroll
    for (int ct = 0; ct < 8; ++ct) {
#pragma unroll
        for (int r = 0; r < 4; ++r) {
            int g = orow0 + r;
            if (g < N) {
                __half hh = __float2half(acc[ct][r]);
                Hh[(size_t)g * 128 + ct * 16 + ocol] = __half_as_ushort(hh);
            }
        }
    }
}

// fused: out = relu(LN(bias + sum_e ew*H[src])); 4 nodes per wave (16 lanes each).
// lane owns features 8*l16 .. 8*l16+7 (one uint4 = full row slice per edge).
template <bool FINAL>
__global__ __launch_bounds__(256) void k_agg_ln(const unsigned short* __restrict__ Hh,
                                                const unsigned int* __restrict__ edata,
                                                const uint2* __restrict__ nfo,
                                                const float* __restrict__ bias,
                                                const float* __restrict__ g,
                                                const float* __restrict__ be,
                                                unsigned short* __restrict__ outb,
                                                void* __restrict__ outAny,
                                                const int* __restrict__ flags, int N) {
    int t = threadIdx.x;
    int l16 = t & 15;
    int node = blockIdx.x * 16 + (t >> 4);
    if (node >= N) return;
    uint2 info = nfo[node];
    int base = (int)info.x, deg = (int)info.y;
    __half2 a01 = u2h2(0u), a23 = u2h2(0u), a45 = u2h2(0u), a67 = u2h2(0u);
    const uint4* Hl = (const uint4*)Hh + l16;   // + (row << 4)
    for (int b0 = 0; b0 < deg; b0 += 8) {
        const uint4* ep = (const uint4*)(edata + base + b0);
        uint4 q0 = ep[0], q1 = ep[1];
        uint4 h0 = Hl[(size_t)(q0.x & 0xffffu) << 4];
        uint4 h1 = Hl[(size_t)(q0.y & 0xffffu) << 4];
        uint4 h2 = Hl[(size_t)(q0.z & 0xffffu) << 4];
        uint4 h3 = Hl[(size_t)(q0.w & 0xffffu) << 4];
        uint4 h4 = Hl[(size_t)(q1.x & 0xffffu) << 4];
        uint4 h5 = Hl[(size_t)(q1.y & 0xffffu) << 4];
        uint4 h6 = Hl[(size_t)(q1.z & 0xffffu) << 4];
        uint4 h7 = Hl[(size_t)(q1.w & 0xffffu) << 4];
        unsigned int wb; __half2 w2;
#define ACC8(hh, wsrc)                                                        \
        wb = (wsrc) >> 16; w2 = u2h2(wb | (wb << 16));                        \
        a01 = __hfma2(u2h2(hh.x), w2, a01); a23 = __hfma2(u2h2(hh.y), w2, a23); \
        a45 = __hfma2(u2h2(hh.z), w2, a45); a67 = __hfma2(u2h2(hh.w), w2, a67);
        ACC8(h0, q0.x) ACC8(h1, q0.y) ACC8(h2, q0.z) ACC8(h3, q0.w)
        ACC8(h4, q1.x) ACC8(h5, q1.y) ACC8(h6, q1.z) ACC8(h7, q1.w)
#undef ACC8
    }
    float4 bv0 = ((const float4*)bias)[2 * l16];
    float4 bv1 = ((const float4*)bias)[2 * l16 + 1];
    float a0 = __low2float(a01) + bv0.x, a1 = __high2float(a01) + bv0.y;
    float a2 = __low2float(a23) + bv0.z, a3 = __high2float(a23) + bv0.w;
    float a4 = __low2float(a45) + bv1.x, a5 = __high2float(a45) + bv1.y;
    float a6 = __low2float(a67) + bv1.z, a7 = __high2float(a67) + bv1.w;
    // LayerNorm over 128 features spread 8-per-lane across 16 lanes
    float s = ((a0 + a1) + (a2 + a3)) + ((a4 + a5) + (a6 + a7));
#pragma unroll
    for (int m = 8; m >= 1; m >>= 1) s += __shfl_xor(s, m, 64);
    float mu = s * (1.f / 128.f);
    float d0 = a0 - mu, d1 = a1 - mu, d2 = a2 - mu, d3 = a3 - mu;
    float d4 = a4 - mu, d5 = a5 - mu, d6 = a6 - mu, d7 = a7 - mu;
    float q = ((d0 * d0 + d1 * d1) + (d2 * d2 + d3 * d3)) +
              ((d4 * d4 + d5 * d5) + (d6 * d6 + d7 * d7));
#pragma unroll
    for (int m = 8; m >= 1; m >>= 1) q += __shfl_xor(q, m, 64);
    float rs = rsqrtf(q * (1.f / 128.f) + LN_EPS);
    float4 gv0 = ((const float4*)g)[2 * l16], gv1 = ((const float4*)g)[2 * l16 + 1];
    float4 bev0 = ((const float4*)be)[2 * l16], bev1 = ((const float4*)be)[2 * l16 + 1];
    float r0 = fmaxf(d0 * rs * gv0.x + bev0.x, 0.f);
    float r1 = fmaxf(d1 * rs * gv0.y + bev0.y, 0.f);
    float r2 = fmaxf(d2 * rs * gv0.z + bev0.z, 0.f);
    float r3 = fmaxf(d3 * rs * gv0.w + bev0.w, 0.f);
    float r4 = fmaxf(d4 * rs * gv1.x + bev1.x, 0.f);
    float r5 = fmaxf(d5 * rs * gv1.y + bev1.y, 0.f);
    float r6 = fmaxf(d6 * rs * gv1.z + bev1.z, 0.f);
    float r7 = fmaxf(d7 * rs * gv1.w + bev1.w, 0.f);
    if (FINAL) {
        if (flags[0]) {
            float4* o = (float4*)outAny + (size_t)node * 32 + 2 * l16;
            o[0] = make_float4(r0, r1, r2, r3);
            o[1] = make_float4(r4, r5, r6, r7);
        } else {
            uint4 o;
            o.x = pk2(r0, r1); o.y = pk2(r2, r3);
            o.z = pk2(r4, r5); o.w = pk2(r6, r7);
            ((uint4*)outAny)[(size_t)node * 16 + l16] = o;
        }
    } else {
        uint4 o;
        o.x = pk2(r0, r1); o.y = pk2(r2, r3);
        o.z = pk2(r4, r5); o.w = pk2(r6, r7);
        ((uint4*)outb)[(size_t)node * 16 + l16] = o;
    }
}

extern "C" void kernel_launch(void* const* d_in, const int* in_sizes, int n_in,
                              void* d_out, int out_size, void* d_ws, size_t ws_size,
                              hipStream_t stream) {
    const unsigned short* x_u16 = (const unsigned short*)d_in[0];
    const int*            ei    = (const int*)d_in[1];

    const int N = in_sizes[0] / 128;
    const int E = in_sizes[2];
    const int B = (N + 255) >> 8;          // buckets of 256 nodes (<=256)
    const int chunk = (E + G1 - 1) / G1;

    // ---- workspace layout ----
    unsigned short* Xb = (unsigned short*)d_ws;            // N*128 bf16 (mid act)
    unsigned short* Hh = Xb + (size_t)N * 128;             // N*128 f16
    unsigned int* gA    = (unsigned int*)(Hh + (size_t)N * 128); // E
    unsigned int* edata = gA + E;                          // B*CAPB
    unsigned char* g8   = (unsigned char*)(edata + (size_t)B * CAPB); // E (pad 4)
    int* cnt2d  = (int*)(g8 + ((E + 3) & ~3));             // 256*256
    int* lofs2d = cnt2d + 65536;                           // 256*256
    uint2* nfo  = (uint2*)(lofs2d + 65536);                // N
    int* flags  = (int*)(nfo + N);                         // 8
    unsigned short* Wt1 = (unsigned short*)(flags + 8);    // 16384 bf16
    unsigned short* Wt2 = Wt1 + 16384;                     // 16384 bf16
    float* sm   = (float*)(Wt2 + 16384);                   // 6*128 f32
    float* b1f  = sm;
    float* b2f_ = sm + 128;
    float* g1f  = sm + 256;
    float* g2f  = sm + 384;
    float* be1f = sm + 512;
    float* be2f = sm + 640;

    const int nodeBlocks = (N + 15) / 16;
    const int gemmBlocks = (N + 63) / 64;

    // ---- CSR build (p1 also detects dtypes and publishes flags) ----
    k_p1<<<G1, 256, 0, stream>>>(x_u16, ei, d_in[2], E, B, chunk, gA, g8, cnt2d, lofs2d, flags);
    k_prep<<<64, 256, 0, stream>>>(d_in[3], d_in[5], d_in[4], d_in[6],
                                   d_in[7], d_in[9], d_in[8], d_in[10],
                                   Wt1, Wt2, sm, flags);
    k_p3<<<B, 256, 0, stream>>>(gA, g8, cnt2d, lofs2d, edata, nfo, N, B, chunk);

    // ---- layer 1 (GEMM reads d_in[0] directly, converts in staging) ----
    k_gemm<<<gemmBlocks, 256, 0, stream>>>(d_in[0], Wt1, Hh, N, flags, 1);
    k_agg_ln<false><<<nodeBlocks, 256, 0, stream>>>(Hh, edata, nfo, b1f, g1f, be1f, Xb, nullptr, flags, N);

    // ---- layer 2 ----
    k_gemm<<<gemmBlocks, 256, 0, stream>>>(Xb, Wt2, Hh, N, flags, 0);
    k_agg_ln<true><<<nodeBlocks, 256, 0, stream>>>(Hh, edata, nfo, b2f_, g2f, be2f, nullptr, d_out, flags, N);
}